// Round 1
// baseline (1966.681 us; speedup 1.0000x reference)
//
#include <hip/hip_runtime.h>
#include <math.h>

#define B_ 4
#define S_ 2048
#define H_ 768
#define NH_ 12
#define HD_ 64
#define BSH (B_ * S_ * H_)
#define NROWS (B_ * S_)

// ---------------------------------------------------------------------------
// depthwise conv1d k=3, padding=1, over sequence dim; in/out layout [B,S,H]
// dw[b,s,h] = sum_j prev[b,s+j-1,h] * w3[h*3+j] + bias[h]
// ---------------------------------------------------------------------------
__global__ __launch_bounds__(256) void dwconv_k(const float* __restrict__ prev,
                                                const float* __restrict__ w3,
                                                const float* __restrict__ bias,
                                                float* __restrict__ out) {
  int row = blockIdx.x;           // b*S + s
  int s = row & (S_ - 1);         // S_ = 2048 (pow2)
  size_t base = (size_t)row * H_;
  for (int h = threadIdx.x; h < H_; h += 256) {
    float acc = bias[h] + prev[base + h] * w3[h * 3 + 1];
    if (s > 0)      acc += prev[base - H_ + h] * w3[h * 3 + 0];
    if (s < S_ - 1) acc += prev[base + H_ + h] * w3[h * 3 + 2];
    out[base + h] = acc;
  }
}

// ---------------------------------------------------------------------------
// C[m,n] = sum_k A[m,k] * W[n,k] + bias[n]   (W row-major [N,K], i.e. B^T GEMM)
// act==1: exact GELU.  Tile 128x128, BK=16, 8x8 microtile, 256 threads.
// LDS stored k-major so fragment reads are ds_read_b128.
// ---------------------------------------------------------------------------
__global__ __launch_bounds__(256) void gemm_bt(const float* __restrict__ A,
                                               const float* __restrict__ W,
                                               const float* __restrict__ bias,
                                               float* __restrict__ C,
                                               int M, int N, int K, int act) {
  __shared__ float AsT[16][132];  // [k][m], pad 132 (132*4B = 33*16 -> rows 16B aligned)
  __shared__ float WsT[16][132];  // [k][n]
  int tid = threadIdx.x;
  int tx = tid & 15, ty = tid >> 4;
  int m0 = blockIdx.y * 128, n0 = blockIdx.x * 128;

  // load mapping: 512 float4 per tile per matrix, 2 per thread
  int r0 = tid >> 2;              // 0..63
  int c4 = (tid & 3) * 4;         // 0,4,8,12
  const float* Ap0 = A + (size_t)(m0 + r0) * K + c4;
  const float* Ap1 = A + (size_t)(m0 + r0 + 64) * K + c4;
  const float* Wp0 = W + (size_t)(n0 + r0) * K + c4;
  const float* Wp1 = W + (size_t)(n0 + r0 + 64) * K + c4;

  float acc[8][8] = {};

  for (int kt = 0; kt < K; kt += 16) {
    float4 a0 = *(const float4*)(Ap0 + kt);
    float4 a1 = *(const float4*)(Ap1 + kt);
    float4 w0 = *(const float4*)(Wp0 + kt);
    float4 w1 = *(const float4*)(Wp1 + kt);
    __syncthreads();  // previous tile's compute done before overwrite
    AsT[c4 + 0][r0] = a0.x; AsT[c4 + 1][r0] = a0.y; AsT[c4 + 2][r0] = a0.z; AsT[c4 + 3][r0] = a0.w;
    AsT[c4 + 0][r0 + 64] = a1.x; AsT[c4 + 1][r0 + 64] = a1.y; AsT[c4 + 2][r0 + 64] = a1.z; AsT[c4 + 3][r0 + 64] = a1.w;
    WsT[c4 + 0][r0] = w0.x; WsT[c4 + 1][r0] = w0.y; WsT[c4 + 2][r0] = w0.z; WsT[c4 + 3][r0] = w0.w;
    WsT[c4 + 0][r0 + 64] = w1.x; WsT[c4 + 1][r0 + 64] = w1.y; WsT[c4 + 2][r0 + 64] = w1.z; WsT[c4 + 3][r0 + 64] = w1.w;
    __syncthreads();
#pragma unroll
    for (int kk = 0; kk < 16; ++kk) {
      float ar[8], br[8];
      *(float4*)&ar[0] = *(const float4*)&AsT[kk][ty * 8];
      *(float4*)&ar[4] = *(const float4*)&AsT[kk][ty * 8 + 4];
      *(float4*)&br[0] = *(const float4*)&WsT[kk][tx * 8];
      *(float4*)&br[4] = *(const float4*)&WsT[kk][tx * 8 + 4];
#pragma unroll
      for (int i = 0; i < 8; ++i)
#pragma unroll
        for (int j = 0; j < 8; ++j)
          acc[i][j] += ar[i] * br[j];
    }
  }

#pragma unroll
  for (int i = 0; i < 8; ++i) {
    int m = m0 + ty * 8 + i;
#pragma unroll
    for (int j4 = 0; j4 < 8; j4 += 4) {
      int n = n0 + tx * 8 + j4;
      float4 c;
      c.x = acc[i][j4 + 0] + bias[n + 0];
      c.y = acc[i][j4 + 1] + bias[n + 1];
      c.z = acc[i][j4 + 2] + bias[n + 2];
      c.w = acc[i][j4 + 3] + bias[n + 3];
      if (act) {
        c.x = 0.5f * c.x * (1.0f + erff(c.x * 0.70710678118f));
        c.y = 0.5f * c.y * (1.0f + erff(c.y * 0.70710678118f));
        c.z = 0.5f * c.z * (1.0f + erff(c.z * 0.70710678118f));
        c.w = 0.5f * c.w * (1.0f + erff(c.w * 0.70710678118f));
      }
      *(float4*)&C[(size_t)m * N + n] = c;
    }
  }
}

// ---------------------------------------------------------------------------
// LayerNorm in-place over last dim (H=768), one block per row, 3 elems/thread
// ---------------------------------------------------------------------------
__global__ __launch_bounds__(256) void ln_inplace(float* __restrict__ X,
                                                  const float* __restrict__ g,
                                                  const float* __restrict__ bb) {
  int row = blockIdx.x;
  size_t base = (size_t)row * H_;
  int h0 = threadIdx.x, h1 = h0 + 256, h2 = h0 + 512;
  float x0 = X[base + h0], x1 = X[base + h1], x2 = X[base + h2];
  float s = x0 + x1 + x2;
  float s2 = x0 * x0 + x1 * x1 + x2 * x2;
  for (int off = 32; off > 0; off >>= 1) {
    s += __shfl_down(s, off);
    s2 += __shfl_down(s2, off);
  }
  __shared__ float sa[4], sq[4], st[2];
  int wid = threadIdx.x >> 6, lane = threadIdx.x & 63;
  if (lane == 0) { sa[wid] = s; sq[wid] = s2; }
  __syncthreads();
  if (threadIdx.x == 0) {
    float ts = sa[0] + sa[1] + sa[2] + sa[3];
    float ts2 = sq[0] + sq[1] + sq[2] + sq[3];
    float mean = ts * (1.0f / H_);
    float var = ts2 * (1.0f / H_) - mean * mean;
    st[0] = mean;
    st[1] = rsqrtf(var + 1e-5f);
  }
  __syncthreads();
  float mean = st[0], rstd = st[1];
  X[base + h0] = (x0 - mean) * rstd * g[h0] + bb[h0];
  X[base + h1] = (x1 - mean) * rstd * g[h1] + bb[h1];
  X[base + h2] = (x2 - mean) * rstd * g[h2] + bb[h2];
}

// ---------------------------------------------------------------------------
// Flash-style non-causal attention. grid (S/64, NH, B), 256 threads (16x16).
// q is [B,S,H] with head slice n*64; OUTPUT written in-place over q (each
// block reads only its own q-tile into LDS first -> safe).
// ---------------------------------------------------------------------------
__global__ __launch_bounds__(256) void attn_k(float* __restrict__ q,
                                              const float* __restrict__ k,
                                              const float* __restrict__ v) {
  __shared__ float Qs[64][65];
  __shared__ float Ks[64][65];
  __shared__ float Vs[64][65];
  __shared__ float Ps[64][65];
  __shared__ float red[64][17];
  __shared__ float mrow[64], lrow[64], arow[64];
  int tid = threadIdx.x;
  int tx = tid & 15, ty = tid >> 4;
  int b = blockIdx.z, n = blockIdx.y, q0 = blockIdx.x * 64;
  size_t qbase = ((size_t)(b * S_ + q0)) * H_ + n * HD_;

#pragma unroll
  for (int it = 0; it < 4; ++it) {
    int ff = tid + it * 256;
    int row = ff >> 4, c4 = (ff & 15) * 4;
    float4 val = *(const float4*)(q + qbase + (size_t)row * H_ + c4);
    Qs[row][c4 + 0] = val.x; Qs[row][c4 + 1] = val.y;
    Qs[row][c4 + 2] = val.z; Qs[row][c4 + 3] = val.w;
  }
  if (tid < 64) { mrow[tid] = -INFINITY; lrow[tid] = 0.f; }
  float o[4][4] = {};

  for (int kt = 0; kt < S_; kt += 64) {
    __syncthreads();  // prev PV done (and Q/stat init on first iter)
    size_t kbase = ((size_t)(b * S_ + kt)) * H_ + n * HD_;
#pragma unroll
    for (int it = 0; it < 4; ++it) {
      int ff = tid + it * 256;
      int row = ff >> 4, c4 = (ff & 15) * 4;
      float4 kv = *(const float4*)(k + kbase + (size_t)row * H_ + c4);
      float4 vv = *(const float4*)(v + kbase + (size_t)row * H_ + c4);
      Ks[row][c4 + 0] = kv.x; Ks[row][c4 + 1] = kv.y;
      Ks[row][c4 + 2] = kv.z; Ks[row][c4 + 3] = kv.w;
      Vs[row][c4 + 0] = vv.x; Vs[row][c4 + 1] = vv.y;
      Vs[row][c4 + 2] = vv.z; Vs[row][c4 + 3] = vv.w;
    }
    __syncthreads();

    float s[4][4] = {};
    for (int d = 0; d < 64; ++d) {
      float qr[4], kr[4];
#pragma unroll
      for (int i = 0; i < 4; ++i) qr[i] = Qs[ty + 16 * i][d];
#pragma unroll
      for (int j = 0; j < 4; ++j) kr[j] = Ks[tx + 16 * j][d];
#pragma unroll
      for (int i = 0; i < 4; ++i)
#pragma unroll
        for (int j = 0; j < 4; ++j)
          s[i][j] += qr[i] * kr[j];
    }

#pragma unroll
    for (int i = 0; i < 4; ++i) {
      float lm = -INFINITY;
#pragma unroll
      for (int j = 0; j < 4; ++j) { s[i][j] *= 0.125f; lm = fmaxf(lm, s[i][j]); }
      red[ty + 16 * i][tx] = lm;
    }
    __syncthreads();
    if (tid < 64) {
      float mx = red[tid][0];
      for (int t = 1; t < 16; ++t) mx = fmaxf(mx, red[tid][t]);
      float mnew = fmaxf(mrow[tid], mx);
      float al = __expf(mrow[tid] - mnew);  // -inf -> 0 on first tile
      arow[tid] = al;
      lrow[tid] *= al;
      mrow[tid] = mnew;
    }
    __syncthreads();
#pragma unroll
    for (int i = 0; i < 4; ++i) {
      int r = ty + 16 * i;
      float mv = mrow[r], al = arow[r], rs = 0.f;
#pragma unroll
      for (int j = 0; j < 4; ++j) {
        float p = __expf(s[i][j] - mv);
        Ps[r][tx + 16 * j] = p;
        rs += p;
        o[i][j] *= al;
      }
      red[r][tx] = rs;
    }
    __syncthreads();
    if (tid < 64) {
      float t = 0.f;
      for (int u = 0; u < 16; ++u) t += red[tid][u];
      lrow[tid] += t;
    }
    for (int kk = 0; kk < 64; ++kk) {
      float pr[4], vr[4];
#pragma unroll
      for (int i = 0; i < 4; ++i) pr[i] = Ps[ty + 16 * i][kk];
#pragma unroll
      for (int j = 0; j < 4; ++j) vr[j] = Vs[kk][tx + 16 * j];
#pragma unroll
      for (int i = 0; i < 4; ++i)
#pragma unroll
        for (int j = 0; j < 4; ++j)
          o[i][j] += pr[i] * vr[j];
    }
  }
  __syncthreads();  // final lrow updates visible
#pragma unroll
  for (int i = 0; i < 4; ++i) {
    float inv = 1.0f / lrow[ty + 16 * i];
#pragma unroll
    for (int j = 0; j < 4; ++j)
      q[qbase + (size_t)(ty + 16 * i) * H_ + tx + 16 * j] = o[i][j] * inv;
  }
}

// ---------------------------------------------------------------------------
// gate = sigmoid([x,bridged] . Wg + bg); out = x + mask*gate*tanh(inj);
// paux[row] = mask * sum_h (bridged-x)^2.  One block per row.
// ---------------------------------------------------------------------------
__global__ __launch_bounds__(256) void gate_out_k(const float* __restrict__ x,
                                                  const float* __restrict__ br,
                                                  const float* __restrict__ inj,
                                                  const int* __restrict__ mask,
                                                  const float* __restrict__ Wg,
                                                  const float* __restrict__ bg,
                                                  float* __restrict__ out,
                                                  float* __restrict__ paux) {
  int row = blockIdx.x;
  int b = row >> 11;  // S_ = 2048
  size_t base = (size_t)row * H_;
  float dot = 0.f, aux = 0.f;
  for (int h = threadIdx.x; h < H_; h += 256) {
    float xv = x[base + h], bv = br[base + h];
    dot += xv * Wg[h] + bv * Wg[H_ + h];
    float d = bv - xv;
    aux += d * d;
  }
  for (int off = 32; off > 0; off >>= 1) {
    dot += __shfl_down(dot, off);
    aux += __shfl_down(aux, off);
  }
  __shared__ float sd[4], sx[4], gsh[2];
  int wid = threadIdx.x >> 6, lane = threadIdx.x & 63;
  if (lane == 0) { sd[wid] = dot; sx[wid] = aux; }
  __syncthreads();
  if (threadIdx.x == 0) {
    float td = sd[0] + sd[1] + sd[2] + sd[3];
    float ta = sx[0] + sx[1] + sx[2] + sx[3];
    gsh[0] = 1.0f / (1.0f + expf(-(td + bg[0])));
    gsh[1] = ta;
  }
  __syncthreads();
  float mf = (mask[b] != 0) ? 1.0f : 0.0f;
  float gm = gsh[0] * mf;
  for (int h = threadIdx.x; h < H_; h += 256)
    out[base + h] = x[base + h] + gm * tanhf(inj[base + h]);
  if (threadIdx.x == 0) paux[row] = mf * gsh[1];
}

// ---------------------------------------------------------------------------
// aux = sum(paux) / (max(nmask,1) * S * H)
// ---------------------------------------------------------------------------
__global__ __launch_bounds__(256) void aux_reduce_k(const float* __restrict__ paux,
                                                    const int* __restrict__ mask,
                                                    float* __restrict__ outp) {
  float s = 0.f;
  for (int i = threadIdx.x; i < NROWS; i += 256) s += paux[i];
  for (int off = 32; off > 0; off >>= 1) s += __shfl_down(s, off);
  __shared__ float sw[4];
  int wid = threadIdx.x >> 6, lane = threadIdx.x & 63;
  if (lane == 0) sw[wid] = s;
  __syncthreads();
  if (threadIdx.x == 0) {
    float t = sw[0] + sw[1] + sw[2] + sw[3];
    int nm = (mask[0] != 0) + (mask[1] != 0) + (mask[2] != 0) + (mask[3] != 0);
    if (nm < 1) nm = 1;
    outp[0] = t / ((float)nm * (float)(S_ * H_));
  }
}

// ---------------------------------------------------------------------------
extern "C" void kernel_launch(void* const* d_in, const int* in_sizes, int n_in,
                              void* d_out, int out_size, void* d_ws, size_t ws_size,
                              hipStream_t stream) {
  const float* x     = (const float*)d_in[0];
  const float* prev  = (const float*)d_in[1];
  const int*   mask  = (const int*)d_in[2];
  const float* dw_w  = (const float*)d_in[3];
  const float* dw_b  = (const float*)d_in[4];
  const float* pw_w  = (const float*)d_in[5];
  const float* pw_b  = (const float*)d_in[6];
  const float* cn_g  = (const float*)d_in[7];
  const float* cn_b  = (const float*)d_in[8];
  const float* Wq    = (const float*)d_in[9];
  const float* bq    = (const float*)d_in[10];
  const float* Wk    = (const float*)d_in[11];
  const float* bk    = (const float*)d_in[12];
  const float* Wv    = (const float*)d_in[13];
  const float* bv    = (const float*)d_in[14];
  const float* Wo    = (const float*)d_in[15];
  const float* bo    = (const float*)d_in[16];
  const float* pn_g  = (const float*)d_in[17];
  const float* pn_b  = (const float*)d_in[18];
  const float* Wpost = (const float*)d_in[19];
  const float* bpost = (const float*)d_in[20];
  const float* Wg    = (const float*)d_in[21];
  const float* bg    = (const float*)d_in[22];
  float* out = (float*)d_out;

  float* W0 = (float*)d_ws;   // bridged
  float* W1 = W0 + BSH;       // dw -> q -> ao (attn writes in-place)
  float* W2 = W1 + BSH;       // k -> ao_proj -> ln(pn)
  float* W3 = W2 + BSH;       // v -> inj
  float* paux = W3 + BSH;     // [NROWS]

  dim3 ggrid(H_ / 128, NROWS / 128);  // (6, 64)

  // 1. depthwise conv: prev -> W1
  dwconv_k<<<NROWS, 256, 0, stream>>>(prev, dw_w, dw_b, W1);
  // 2. pointwise conv + GELU: W1 -> W0
  gemm_bt<<<ggrid, 256, 0, stream>>>(W1, pw_w, pw_b, W0, NROWS, H_, H_, 1);
  // 3. conv-norm LN in-place -> bridged
  ln_inplace<<<NROWS, 256, 0, stream>>>(W0, cn_g, cn_b);
  // 4-6. q,k,v projections
  gemm_bt<<<ggrid, 256, 0, stream>>>(x,  Wq, bq, W1, NROWS, H_, H_, 0);
  gemm_bt<<<ggrid, 256, 0, stream>>>(W0, Wk, bk, W2, NROWS, H_, H_, 0);
  gemm_bt<<<ggrid, 256, 0, stream>>>(W0, Wv, bv, W3, NROWS, H_, H_, 0);
  // 7. attention: q(W1),k(W2),v(W3) -> ao in-place into W1
  attn_k<<<dim3(S_ / 64, NH_, B_), 256, 0, stream>>>(W1, W2, W3);
  // 8. output projection: W1 -> W2
  gemm_bt<<<ggrid, 256, 0, stream>>>(W1, Wo, bo, W2, NROWS, H_, H_, 0);
  // 9. post-attn LN in-place
  ln_inplace<<<NROWS, 256, 0, stream>>>(W2, pn_g, pn_b);
  // 10. post linear: W2 -> W3 (inj)
  gemm_bt<<<ggrid, 256, 0, stream>>>(W2, Wpost, bpost, W3, NROWS, H_, H_, 0);
  // 11. gate + masked residual + aux partials
  gate_out_k<<<NROWS, 256, 0, stream>>>(x, W0, W3, mask, Wg, bg, out, paux);
  // 12. aux reduction -> out[BSH]
  aux_reduce_k<<<1, 256, 0, stream>>>(paux, mask, out + BSH);
}

// Round 2
// 650.329 us; speedup vs baseline: 3.0241x; 3.0241x over previous
//
#include <hip/hip_runtime.h>
#include <math.h>

#define B_ 4
#define S_ 2048
#define H_ 768
#define NH_ 12
#define HD_ 64
#define BSH (B_ * S_ * H_)
#define NROWS (B_ * S_)

typedef __attribute__((ext_vector_type(8))) short bf16x8;
typedef __attribute__((ext_vector_type(4))) short s16x4;
typedef __attribute__((ext_vector_type(4))) float f32x4;

// fp32 -> bf16 (RNE), finite inputs
__device__ __forceinline__ short f2bf(float f) {
  union { float f; unsigned u; } x; x.f = f;
  unsigned r = x.u + 0x7FFF + ((x.u >> 16) & 1);
  return (short)(r >> 16);
}

// ---------------------------------------------------------------------------
// depthwise conv1d k=3, padding=1, over sequence dim; layout [B,S,H]
// ---------------------------------------------------------------------------
__global__ __launch_bounds__(256) void dwconv_k(const float* __restrict__ prev,
                                                const float* __restrict__ w3,
                                                const float* __restrict__ bias,
                                                float* __restrict__ out) {
  int row = blockIdx.x;
  int s = row & (S_ - 1);
  size_t base = (size_t)row * H_;
  for (int h = threadIdx.x; h < H_; h += 256) {
    float acc = bias[h] + prev[base + h] * w3[h * 3 + 1];
    if (s > 0)      acc += prev[base - H_ + h] * w3[h * 3 + 0];
    if (s < S_ - 1) acc += prev[base + H_ + h] * w3[h * 3 + 2];
    out[base + h] = acc;
  }
}

// ---------------------------------------------------------------------------
// C[m,n] = sum_k A[m,k]*W[n,k] + bias[n]; optional exact GELU.
// bf16 MFMA 16x16x32, 128x128 tile, BK=32, 4 waves, 4x4 accs/wave.
// fp32 global inputs cast to bf16 during LDS staging; fp32 accumulate/output.
// ---------------------------------------------------------------------------
__global__ __launch_bounds__(256) void gemm_bt_mfma(const float* __restrict__ A,
                                                    const float* __restrict__ W,
                                                    const float* __restrict__ bias,
                                                    float* __restrict__ C,
                                                    int M, int N, int K, int act) {
  __shared__ short As[128][40];  // [m][k], pad 32->40 (80B pitch, 16B-mult)
  __shared__ short Ws[128][40];  // [n][k]
  int tid = threadIdx.x;
  int lane = tid & 63, w = tid >> 6;
  int wr = w >> 1, wc = w & 1;
  int lm = lane & 15, lq = lane >> 4;
  int m0 = blockIdx.y * 128, n0 = blockIdx.x * 128;
  int srow = tid >> 1, skq = (tid & 1) * 16;  // 2 threads/row, 16 k each
  const float* Ap = A + (size_t)(m0 + srow) * K + skq;
  const float* Wp = W + (size_t)(n0 + srow) * K + skq;

  f32x4 acc[4][4];
#pragma unroll
  for (int i = 0; i < 4; ++i)
#pragma unroll
    for (int j = 0; j < 4; ++j) acc[i][j] = (f32x4){0.f, 0.f, 0.f, 0.f};

  for (int kt = 0; kt < K; kt += 32) {
    float4 av[4], wv[4];
#pragma unroll
    for (int i = 0; i < 4; ++i) {
      av[i] = *(const float4*)(Ap + kt + i * 4);
      wv[i] = *(const float4*)(Wp + kt + i * 4);
    }
    __syncthreads();  // previous tile's frag reads done
    short ta[16], tw[16];
#pragma unroll
    for (int i = 0; i < 4; ++i) {
      ta[i*4+0] = f2bf(av[i].x); ta[i*4+1] = f2bf(av[i].y);
      ta[i*4+2] = f2bf(av[i].z); ta[i*4+3] = f2bf(av[i].w);
      tw[i*4+0] = f2bf(wv[i].x); tw[i*4+1] = f2bf(wv[i].y);
      tw[i*4+2] = f2bf(wv[i].z); tw[i*4+3] = f2bf(wv[i].w);
    }
    *(bf16x8*)&As[srow][skq]     = *(bf16x8*)&ta[0];
    *(bf16x8*)&As[srow][skq + 8] = *(bf16x8*)&ta[8];
    *(bf16x8*)&Ws[srow][skq]     = *(bf16x8*)&tw[0];
    *(bf16x8*)&Ws[srow][skq + 8] = *(bf16x8*)&tw[8];
    __syncthreads();
    bf16x8 af[4], bw[4];
#pragma unroll
    for (int i = 0; i < 4; ++i) af[i] = *(const bf16x8*)&As[wr * 64 + i * 16 + lm][lq * 8];
#pragma unroll
    for (int j = 0; j < 4; ++j) bw[j] = *(const bf16x8*)&Ws[wc * 64 + j * 16 + lm][lq * 8];
#pragma unroll
    for (int i = 0; i < 4; ++i)
#pragma unroll
      for (int j = 0; j < 4; ++j)
        acc[i][j] = __builtin_amdgcn_mfma_f32_16x16x32_bf16(af[i], bw[j], acc[i][j], 0, 0, 0);
  }

#pragma unroll
  for (int i = 0; i < 4; ++i) {
    int mrow = m0 + wr * 64 + i * 16 + lq * 4;  // C row = quad*4+reg
#pragma unroll
    for (int j = 0; j < 4; ++j) {
      int col = n0 + wc * 64 + j * 16 + lm;     // C col = lane&15
      float bn = bias[col];
#pragma unroll
      for (int r = 0; r < 4; ++r) {
        float cv = acc[i][j][r] + bn;
        if (act) cv = 0.5f * cv * (1.0f + erff(cv * 0.70710678118f));
        C[(size_t)(mrow + r) * N + col] = cv;
      }
    }
  }
}

// ---------------------------------------------------------------------------
// LayerNorm in-place over last dim (H=768)
// ---------------------------------------------------------------------------
__global__ __launch_bounds__(256) void ln_inplace(float* __restrict__ X,
                                                  const float* __restrict__ g,
                                                  const float* __restrict__ bb) {
  int row = blockIdx.x;
  size_t base = (size_t)row * H_;
  int h0 = threadIdx.x, h1 = h0 + 256, h2 = h0 + 512;
  float x0 = X[base + h0], x1 = X[base + h1], x2 = X[base + h2];
  float s = x0 + x1 + x2;
  float s2 = x0 * x0 + x1 * x1 + x2 * x2;
  for (int off = 32; off > 0; off >>= 1) {
    s += __shfl_down(s, off);
    s2 += __shfl_down(s2, off);
  }
  __shared__ float sa[4], sq[4], st[2];
  int wid = threadIdx.x >> 6, lane = threadIdx.x & 63;
  if (lane == 0) { sa[wid] = s; sq[wid] = s2; }
  __syncthreads();
  if (threadIdx.x == 0) {
    float ts = sa[0] + sa[1] + sa[2] + sa[3];
    float ts2 = sq[0] + sq[1] + sq[2] + sq[3];
    float mean = ts * (1.0f / H_);
    float var = ts2 * (1.0f / H_) - mean * mean;
    st[0] = mean;
    st[1] = rsqrtf(var + 1e-5f);
  }
  __syncthreads();
  float mean = st[0], rstd = st[1];
  X[base + h0] = (x0 - mean) * rstd * g[h0] + bb[h0];
  X[base + h1] = (x1 - mean) * rstd * g[h1] + bb[h1];
  X[base + h2] = (x2 - mean) * rstd * g[h2] + bb[h2];
}

// ---------------------------------------------------------------------------
// MFMA flash attention. grid (S/64, NH, B), 256 threads = 4 waves.
// Wave w owns q rows [q0+w*16, +16): wave-private online softmax.
// K-tile 64. QK^T: Q regs (A) x Ks natural layout (B). PV: P via wave-private
// LDS (C-layout -> A-layout), V register-transposed into Vt[d][sk] (B).
// Output written in-place over q (block reads only its own q rows).
// ---------------------------------------------------------------------------
__global__ __launch_bounds__(256) void attn_mfma(float* __restrict__ q,
                                                 const float* __restrict__ k,
                                                 const float* __restrict__ v) {
  __shared__ short Ks[64][72];  // [sk][d]
  __shared__ short Vt[64][72];  // [d][sk]
  __shared__ short Ps[64][72];  // [q(4 waves x16)][sk], wave-private rows
  int tid = threadIdx.x;
  int lane = tid & 63, w = tid >> 6;
  int lm = lane & 15, lq = lane >> 4;
  int b = blockIdx.z, n = blockIdx.y, q0 = blockIdx.x * 64;
  size_t hoff = (size_t)n * HD_;

  // Q fragments (A-layout): row q0+w*16+lm, d = kk*32 + lq*8 + j; scale 1/8
  bf16x8 qf[2];
  {
    size_t qrow = ((size_t)(b * S_ + q0 + w * 16 + lm)) * H_ + hoff;
#pragma unroll
    for (int kk = 0; kk < 2; ++kk) {
      float4 f0 = *(const float4*)(q + qrow + kk * 32 + lq * 8);
      float4 f1 = *(const float4*)(q + qrow + kk * 32 + lq * 8 + 4);
      short t[8] = { f2bf(f0.x * 0.125f), f2bf(f0.y * 0.125f),
                     f2bf(f0.z * 0.125f), f2bf(f0.w * 0.125f),
                     f2bf(f1.x * 0.125f), f2bf(f1.y * 0.125f),
                     f2bf(f1.z * 0.125f), f2bf(f1.w * 0.125f) };
      qf[kk] = *(bf16x8*)t;
    }
  }
  float m_[4] = {-INFINITY, -INFINITY, -INFINITY, -INFINITY};
  float l_[4] = {0.f, 0.f, 0.f, 0.f};
  f32x4 o[4];
#pragma unroll
  for (int i = 0; i < 4; ++i) o[i] = (f32x4){0.f, 0.f, 0.f, 0.f};

  int ksk = tid >> 2, kd16 = (tid & 3) * 16;  // K staging: row, 16-d chunk
  int vc = tid & 15, vvr = tid >> 4;          // V transpose: d4=vc*4, sk4=vvr*4

  for (int kt = 0; kt < S_; kt += 64) {
    size_t kbase = ((size_t)(b * S_ + kt)) * H_ + hoff;
    float4 kf4[4], vf4[4];
#pragma unroll
    for (int i = 0; i < 4; ++i)
      kf4[i] = *(const float4*)(k + kbase + (size_t)ksk * H_ + kd16 + i * 4);
#pragma unroll
    for (int r = 0; r < 4; ++r)
      vf4[r] = *(const float4*)(v + kbase + (size_t)(vvr * 4 + r) * H_ + vc * 4);
    __syncthreads();  // all waves done reading Ks/Vt from previous tile
    {
      short tk[16];
#pragma unroll
      for (int i = 0; i < 4; ++i) {
        tk[i*4+0] = f2bf(kf4[i].x); tk[i*4+1] = f2bf(kf4[i].y);
        tk[i*4+2] = f2bf(kf4[i].z); tk[i*4+3] = f2bf(kf4[i].w);
      }
      *(bf16x8*)&Ks[ksk][kd16]     = *(bf16x8*)&tk[0];
      *(bf16x8*)&Ks[ksk][kd16 + 8] = *(bf16x8*)&tk[8];
      s16x4 t0 = (s16x4){f2bf(vf4[0].x), f2bf(vf4[1].x), f2bf(vf4[2].x), f2bf(vf4[3].x)};
      s16x4 t1 = (s16x4){f2bf(vf4[0].y), f2bf(vf4[1].y), f2bf(vf4[2].y), f2bf(vf4[3].y)};
      s16x4 t2 = (s16x4){f2bf(vf4[0].z), f2bf(vf4[1].z), f2bf(vf4[2].z), f2bf(vf4[3].z)};
      s16x4 t3 = (s16x4){f2bf(vf4[0].w), f2bf(vf4[1].w), f2bf(vf4[2].w), f2bf(vf4[3].w)};
      *(s16x4*)&Vt[vc * 4 + 0][vvr * 4] = t0;
      *(s16x4*)&Vt[vc * 4 + 1][vvr * 4] = t1;
      *(s16x4*)&Vt[vc * 4 + 2][vvr * 4] = t2;
      *(s16x4*)&Vt[vc * 4 + 3][vvr * 4] = t3;
    }
    __syncthreads();

    // ---- S = Q K^T (rows: quad*4+reg, cols: ni*16+lm) ----
    f32x4 s[4];
#pragma unroll
    for (int ni = 0; ni < 4; ++ni) {
      bf16x8 kb0 = *(const bf16x8*)&Ks[ni * 16 + lm][lq * 8];
      bf16x8 kb1 = *(const bf16x8*)&Ks[ni * 16 + lm][32 + lq * 8];
      s[ni] = (f32x4){0.f, 0.f, 0.f, 0.f};
      s[ni] = __builtin_amdgcn_mfma_f32_16x16x32_bf16(qf[0], kb0, s[ni], 0, 0, 0);
      s[ni] = __builtin_amdgcn_mfma_f32_16x16x32_bf16(qf[1], kb1, s[ni], 0, 0, 0);
    }

    // ---- online softmax (rows wave-private; reduce over 16 lanes of quad) ----
    float mx[4], al[4], rs[4];
#pragma unroll
    for (int r = 0; r < 4; ++r)
      mx[r] = fmaxf(fmaxf(s[0][r], s[1][r]), fmaxf(s[2][r], s[3][r]));
#pragma unroll
    for (int msk = 1; msk < 16; msk <<= 1)
#pragma unroll
      for (int r = 0; r < 4; ++r) mx[r] = fmaxf(mx[r], __shfl_xor(mx[r], msk));
#pragma unroll
    for (int r = 0; r < 4; ++r) {
      float mn = fmaxf(m_[r], mx[r]);
      al[r] = __expf(m_[r] - mn);  // first tile: exp(-inf)=0
      m_[r] = mn;
      rs[r] = 0.f;
    }
#pragma unroll
    for (int ni = 0; ni < 4; ++ni)
#pragma unroll
      for (int r = 0; r < 4; ++r) {
        float p = __expf(s[ni][r] - m_[r]);
        rs[r] += p;
        Ps[w * 16 + lq * 4 + r][ni * 16 + lm] = f2bf(p);
      }
#pragma unroll
    for (int msk = 1; msk < 16; msk <<= 1)
#pragma unroll
      for (int r = 0; r < 4; ++r) rs[r] += __shfl_xor(rs[r], msk);
#pragma unroll
    for (int r = 0; r < 4; ++r) l_[r] = l_[r] * al[r] + rs[r];
#pragma unroll
    for (int nd = 0; nd < 4; ++nd)
#pragma unroll
      for (int r = 0; r < 4; ++r) o[nd][r] *= al[r];

    // ---- O += P V  (P from wave-private LDS rows; same-wave order via lgkmcnt)
    bf16x8 pf0 = *(const bf16x8*)&Ps[w * 16 + lm][lq * 8];
    bf16x8 pf1 = *(const bf16x8*)&Ps[w * 16 + lm][32 + lq * 8];
#pragma unroll
    for (int nd = 0; nd < 4; ++nd) {
      bf16x8 vb0 = *(const bf16x8*)&Vt[nd * 16 + lm][lq * 8];
      bf16x8 vb1 = *(const bf16x8*)&Vt[nd * 16 + lm][32 + lq * 8];
      o[nd] = __builtin_amdgcn_mfma_f32_16x16x32_bf16(pf0, vb0, o[nd], 0, 0, 0);
      o[nd] = __builtin_amdgcn_mfma_f32_16x16x32_bf16(pf1, vb1, o[nd], 0, 0, 0);
    }
  }

  // epilogue: rows q0+w*16+lq*4+r, cols nd*16+lm; write in-place over q
  size_t obase = ((size_t)(b * S_ + q0 + w * 16 + lq * 4)) * H_ + hoff;
#pragma unroll
  for (int r = 0; r < 4; ++r) {
    float inv = 1.0f / l_[r];
#pragma unroll
    for (int nd = 0; nd < 4; ++nd)
      q[obase + (size_t)r * H_ + nd * 16 + lm] = o[nd][r] * inv;
  }
}

// ---------------------------------------------------------------------------
// gate + masked residual + aux partials
// ---------------------------------------------------------------------------
__global__ __launch_bounds__(256) void gate_out_k(const float* __restrict__ x,
                                                  const float* __restrict__ br,
                                                  const float* __restrict__ inj,
                                                  const int* __restrict__ mask,
                                                  const float* __restrict__ Wg,
                                                  const float* __restrict__ bg,
                                                  float* __restrict__ out,
                                                  float* __restrict__ paux) {
  int row = blockIdx.x;
  int b = row >> 11;
  size_t base = (size_t)row * H_;
  float dot = 0.f, aux = 0.f;
  for (int h = threadIdx.x; h < H_; h += 256) {
    float xv = x[base + h], bv = br[base + h];
    dot += xv * Wg[h] + bv * Wg[H_ + h];
    float d = bv - xv;
    aux += d * d;
  }
  for (int off = 32; off > 0; off >>= 1) {
    dot += __shfl_down(dot, off);
    aux += __shfl_down(aux, off);
  }
  __shared__ float sd[4], sx[4], gsh[2];
  int wid = threadIdx.x >> 6, lane = threadIdx.x & 63;
  if (lane == 0) { sd[wid] = dot; sx[wid] = aux; }
  __syncthreads();
  if (threadIdx.x == 0) {
    float td = sd[0] + sd[1] + sd[2] + sd[3];
    float ta = sx[0] + sx[1] + sx[2] + sx[3];
    gsh[0] = 1.0f / (1.0f + expf(-(td + bg[0])));
    gsh[1] = ta;
  }
  __syncthreads();
  float mf = (mask[b] != 0) ? 1.0f : 0.0f;
  float gm = gsh[0] * mf;
  for (int h = threadIdx.x; h < H_; h += 256)
    out[base + h] = x[base + h] + gm * tanhf(inj[base + h]);
  if (threadIdx.x == 0) paux[row] = mf * gsh[1];
}

__global__ __launch_bounds__(256) void aux_reduce_k(const float* __restrict__ paux,
                                                    const int* __restrict__ mask,
                                                    float* __restrict__ outp) {
  float s = 0.f;
  for (int i = threadIdx.x; i < NROWS; i += 256) s += paux[i];
  for (int off = 32; off > 0; off >>= 1) s += __shfl_down(s, off);
  __shared__ float sw[4];
  int wid = threadIdx.x >> 6, lane = threadIdx.x & 63;
  if (lane == 0) sw[wid] = s;
  __syncthreads();
  if (threadIdx.x == 0) {
    float t = sw[0] + sw[1] + sw[2] + sw[3];
    int nm = (mask[0] != 0) + (mask[1] != 0) + (mask[2] != 0) + (mask[3] != 0);
    if (nm < 1) nm = 1;
    outp[0] = t / ((float)nm * (float)(S_ * H_));
  }
}

// ---------------------------------------------------------------------------
extern "C" void kernel_launch(void* const* d_in, const int* in_sizes, int n_in,
                              void* d_out, int out_size, void* d_ws, size_t ws_size,
                              hipStream_t stream) {
  const float* x     = (const float*)d_in[0];
  const float* prev  = (const float*)d_in[1];
  const int*   mask  = (const int*)d_in[2];
  const float* dw_w  = (const float*)d_in[3];
  const float* dw_b  = (const float*)d_in[4];
  const float* pw_w  = (const float*)d_in[5];
  const float* pw_b  = (const float*)d_in[6];
  const float* cn_g  = (const float*)d_in[7];
  const float* cn_b  = (const float*)d_in[8];
  const float* Wq    = (const float*)d_in[9];
  const float* bq    = (const float*)d_in[10];
  const float* Wk    = (const float*)d_in[11];
  const float* bk    = (const float*)d_in[12];
  const float* Wv    = (const float*)d_in[13];
  const float* bv    = (const float*)d_in[14];
  const float* Wo    = (const float*)d_in[15];
  const float* bo    = (const float*)d_in[16];
  const float* pn_g  = (const float*)d_in[17];
  const float* pn_b  = (const float*)d_in[18];
  const float* Wpost = (const float*)d_in[19];
  const float* bpost = (const float*)d_in[20];
  const float* Wg    = (const float*)d_in[21];
  const float* bg    = (const float*)d_in[22];
  float* out = (float*)d_out;

  float* W0 = (float*)d_ws;   // bridged
  float* W1 = W0 + BSH;       // dw -> q -> ao (attn in-place)
  float* W2 = W1 + BSH;       // k -> ao_proj -> ln(pn)
  float* W3 = W2 + BSH;       // v -> inj
  float* paux = W3 + BSH;     // [NROWS]

  dim3 ggrid(H_ / 128, NROWS / 128);  // (6, 64)

  dwconv_k<<<NROWS, 256, 0, stream>>>(prev, dw_w, dw_b, W1);
  gemm_bt_mfma<<<ggrid, 256, 0, stream>>>(W1, pw_w, pw_b, W0, NROWS, H_, H_, 1);
  ln_inplace<<<NROWS, 256, 0, stream>>>(W0, cn_g, cn_b);
  gemm_bt_mfma<<<ggrid, 256, 0, stream>>>(x,  Wq, bq, W1, NROWS, H_, H_, 0);
  gemm_bt_mfma<<<ggrid, 256, 0, stream>>>(W0, Wk, bk, W2, NROWS, H_, H_, 0);
  gemm_bt_mfma<<<ggrid, 256, 0, stream>>>(W0, Wv, bv, W3, NROWS, H_, H_, 0);
  attn_mfma<<<dim3(S_ / 64, NH_, B_), 256, 0, stream>>>(W1, W2, W3);
  gemm_bt_mfma<<<ggrid, 256, 0, stream>>>(W1, Wo, bo, W2, NROWS, H_, H_, 0);
  ln_inplace<<<NROWS, 256, 0, stream>>>(W2, pn_g, pn_b);
  gemm_bt_mfma<<<ggrid, 256, 0, stream>>>(W2, Wpost, bpost, W3, NROWS, H_, H_, 0);
  gate_out_k<<<NROWS, 256, 0, stream>>>(x, W0, W3, mask, Wg, bg, out, paux);
  aux_reduce_k<<<1, 256, 0, stream>>>(paux, mask, out + BSH);
}

// Round 3
// 468.775 us; speedup vs baseline: 4.1954x; 1.3873x over previous
//
#include <hip/hip_runtime.h>
#include <math.h>

#define B_ 4
#define S_ 2048
#define H_ 768
#define NH_ 12
#define HD_ 64
#define BSH (B_ * S_ * H_)
#define NROWS (B_ * S_)
#define WSZ (H_ * H_)  // 589824

typedef __attribute__((ext_vector_type(8))) short bf16x8;
typedef __attribute__((ext_vector_type(4))) short s16x4;
typedef __attribute__((ext_vector_type(4))) float f32x4;

__device__ __forceinline__ short f2bf(float f) {
  union { float f; unsigned u; } x; x.f = f;
  unsigned r = x.u + 0x7FFF + ((x.u >> 16) & 1);
  return (short)(r >> 16);
}
__device__ __forceinline__ float bf2f(short s) {
  union { unsigned u; float f; } x;
  x.u = ((unsigned)(unsigned short)s) << 16;
  return x.f;
}

// async global->LDS, 16B per lane; LDS dst = wave-uniform base + lane*16
typedef __attribute__((address_space(1))) const unsigned int g_u32;
typedef __attribute__((address_space(3))) unsigned int l_u32;
__device__ __forceinline__ void gload16(const void* g, void* l) {
  __builtin_amdgcn_global_load_lds((g_u32*)g, (l_u32*)l, 16, 0, 0);
}

// ---------------------------------------------------------------------------
// fp32 -> bf16 converters
// ---------------------------------------------------------------------------
__global__ __launch_bounds__(256) void cvt_x_k(const float* __restrict__ src,
                                               short* __restrict__ dst) {
  int i = (blockIdx.x * 256 + threadIdx.x) * 4;
  float4 v = *(const float4*)(src + i);
  s16x4 o = {f2bf(v.x), f2bf(v.y), f2bf(v.z), f2bf(v.w)};
  *(s16x4*)(dst + i) = o;
}

__global__ __launch_bounds__(256) void cvt6_k(const float* w0, const float* w1,
                                              const float* w2, const float* w3,
                                              const float* w4, const float* w5,
                                              short* __restrict__ dst) {
  int i = (blockIdx.x * 256 + threadIdx.x) * 4;
  int m = i / WSZ;
  int off = i - m * WSZ;
  const float* s = m == 0 ? w0 : m == 1 ? w1 : m == 2 ? w2 : m == 3 ? w3 : m == 4 ? w4 : w5;
  float4 v = *(const float4*)(s + off);
  s16x4 o = {f2bf(v.x), f2bf(v.y), f2bf(v.z), f2bf(v.w)};
  *(s16x4*)(dst + i) = o;
}

// ---------------------------------------------------------------------------
// depthwise conv1d k=3 pad=1 over seq dim; [B,S,H] fp32 -> bf16
// ---------------------------------------------------------------------------
__global__ __launch_bounds__(256) void dwconv_k(const float* __restrict__ prev,
                                                const float* __restrict__ w3,
                                                const float* __restrict__ bias,
                                                short* __restrict__ out) {
  int row = blockIdx.x;
  int s = row & (S_ - 1);
  size_t base = (size_t)row * H_;
  for (int h = threadIdx.x; h < H_; h += 256) {
    float acc = bias[h] + prev[base + h] * w3[h * 3 + 1];
    if (s > 0)      acc += prev[base - H_ + h] * w3[h * 3 + 0];
    if (s < S_ - 1) acc += prev[base + H_ + h] * w3[h * 3 + 2];
    out[base + h] = f2bf(acc);
  }
}

// ---------------------------------------------------------------------------
// C[m,n] = sum_k A[m,k]*W[n,k] + bias[n]; bf16 in/out, fp32 accum.
// m97 structure: global_load_lds width=16, unpadded [128][32] bf16 tiles,
// BK=32, 16x16x32 MFMA, 4 waves x 4x4 accs. act: exact GELU.
// tout: write output transposed as [B][NH*HD][S] (for V).
// ---------------------------------------------------------------------------
__global__ __launch_bounds__(256) void gemm_bf(const short* __restrict__ A,
                                               const short* __restrict__ W,
                                               const float* __restrict__ bias,
                                               short* __restrict__ C,
                                               int act, int tout) {
  __shared__ short As[4096];  // 128 rows x 32 k (64B rows) - no pad (lds-direct)
  __shared__ short Ws[4096];
  int tid = threadIdx.x, lane = tid & 63, w = tid >> 6;
  int wr = w >> 1, wc = w & 1, lm = lane & 15, lq = lane >> 4;
  int m0 = blockIdx.y * 128, n0 = blockIdx.x * 128;
  // staging: wave w covers rows [w*32, w*32+32); lane -> row w*32+(lane>>2),
  // k-chunk (lane&3)*8; LDS dst = wave base + lane*16B (HW)
  int srow = w * 32 + (lane >> 2);
  int skc = (lane & 3) * 8;
  const short* gA = A + (size_t)(m0 + srow) * H_ + skc;
  const short* gW = W + (size_t)(n0 + srow) * H_ + skc;
  short* lA = As + w * 1024;  // bytes w*2048
  short* lW = Ws + w * 1024;

  f32x4 acc[4][4];
#pragma unroll
  for (int i = 0; i < 4; ++i)
#pragma unroll
    for (int j = 0; j < 4; ++j) acc[i][j] = (f32x4){0.f, 0.f, 0.f, 0.f};

  for (int kt = 0; kt < H_; kt += 32) {
    __syncthreads();  // prev frag reads done
    gload16(gA + kt, lA);
    gload16(gA + kt + 16 * H_, lA + 512);
    gload16(gW + kt, lW);
    gload16(gW + kt + 16 * H_, lW + 512);
    __syncthreads();  // drains vmcnt: LDS tiles ready
    bf16x8 af[4], wf[4];
#pragma unroll
    for (int i = 0; i < 4; ++i) af[i] = *(const bf16x8*)&As[(wr * 64 + i * 16 + lm) * 32 + lq * 8];
#pragma unroll
    for (int j = 0; j < 4; ++j) wf[j] = *(const bf16x8*)&Ws[(wc * 64 + j * 16 + lm) * 32 + lq * 8];
#pragma unroll
    for (int i = 0; i < 4; ++i)
#pragma unroll
      for (int j = 0; j < 4; ++j)
        acc[i][j] = __builtin_amdgcn_mfma_f32_16x16x32_bf16(af[i], wf[j], acc[i][j], 0, 0, 0);
  }

  if (!tout) {
#pragma unroll
    for (int j = 0; j < 4; ++j) {
      int col = n0 + wc * 64 + j * 16 + lm;
      float bn = bias[col];
#pragma unroll
      for (int i = 0; i < 4; ++i) {
        int mrow = m0 + wr * 64 + i * 16 + lq * 4;
#pragma unroll
        for (int r = 0; r < 4; ++r) {
          float cv = acc[i][j][r] + bn;
          if (act) cv = 0.5f * cv * (1.0f + erff(cv * 0.70710678118f));
          C[(size_t)(mrow + r) * H_ + col] = f2bf(cv);
        }
      }
    }
  } else {
    // transposed: dst[b*H + col][s]; 4 C-rows = 4 consecutive s -> packed b64
    int b = m0 >> 11;
    int sb = (m0 & (S_ - 1)) + wr * 64;
#pragma unroll
    for (int j = 0; j < 4; ++j) {
      int col = n0 + wc * 64 + j * 16 + lm;
      float bn = bias[col];
      short* cp = C + ((size_t)(b * H_ + col)) * S_;
#pragma unroll
      for (int i = 0; i < 4; ++i) {
        int s = sb + i * 16 + lq * 4;
        s16x4 pk = {f2bf(acc[i][j][0] + bn), f2bf(acc[i][j][1] + bn),
                    f2bf(acc[i][j][2] + bn), f2bf(acc[i][j][3] + bn)};
        *(s16x4*)(cp + s) = pk;
      }
    }
  }
}

// ---------------------------------------------------------------------------
// LayerNorm over last dim (H=768), bf16 in -> bf16 out (in-place safe)
// ---------------------------------------------------------------------------
__global__ __launch_bounds__(256) void ln_bf(const short* __restrict__ X,
                                             short* __restrict__ Y,
                                             const float* __restrict__ g,
                                             const float* __restrict__ bb) {
  int row = blockIdx.x;
  size_t base = (size_t)row * H_;
  int h0 = threadIdx.x, h1 = h0 + 256, h2 = h0 + 512;
  float x0 = bf2f(X[base + h0]), x1 = bf2f(X[base + h1]), x2 = bf2f(X[base + h2]);
  float s = x0 + x1 + x2;
  float s2 = x0 * x0 + x1 * x1 + x2 * x2;
  for (int off = 32; off > 0; off >>= 1) {
    s += __shfl_down(s, off);
    s2 += __shfl_down(s2, off);
  }
  __shared__ float sa[4], sq[4], st[2];
  int wid = threadIdx.x >> 6, lane = threadIdx.x & 63;
  if (lane == 0) { sa[wid] = s; sq[wid] = s2; }
  __syncthreads();
  if (threadIdx.x == 0) {
    float ts = sa[0] + sa[1] + sa[2] + sa[3];
    float ts2 = sq[0] + sq[1] + sq[2] + sq[3];
    float mean = ts * (1.0f / H_);
    float var = ts2 * (1.0f / H_) - mean * mean;
    st[0] = mean;
    st[1] = rsqrtf(var + 1e-5f);
  }
  __syncthreads();
  float mean = st[0], rstd = st[1];
  Y[base + h0] = f2bf((x0 - mean) * rstd * g[h0] + bb[h0]);
  Y[base + h1] = f2bf((x1 - mean) * rstd * g[h1] + bb[h1]);
  Y[base + h2] = f2bf((x2 - mean) * rstd * g[h2] + bb[h2]);
}

// ---------------------------------------------------------------------------
// Swapped-orientation MFMA flash attention. grid (S/64, NH, B), 4 waves.
// S^T = K Q^T  (A=K rows sk, B=Q^T cols q=lane&15)  -> per-lane softmax state.
// O^T = V^T P^T (A=Vt rows d, B=Ps rows q). Ps [q][sk] serves as B directly.
// qb,kb: [B,S,H] bf16; vtb: [B][H][S] bf16 (pre-transposed); out aob [B,S,H].
// ---------------------------------------------------------------------------
__global__ __launch_bounds__(256) void attn2_k(const short* __restrict__ qb,
                                               const short* __restrict__ kb,
                                               const short* __restrict__ vtb,
                                               short* __restrict__ aob) {
  __shared__ short Ks[64 * 72];      // [sk][d], pad 72
  __shared__ short Vt[64 * 72];      // [d][sk], pad 72
  __shared__ short Ps[4 * 16 * 72];  // per-wave [q16][sk64], pad 72
  int tid = threadIdx.x, lane = tid & 63, w = tid >> 6;
  int lm = lane & 15, lq = lane >> 4;
  int b = blockIdx.z, n = blockIdx.y, q0 = blockIdx.x * 64;
  int hoff = n * HD_;

  // Q^T B-fragments: lane n=q row q0+w*16+lm, k=d
  const short* qrow = qb + ((size_t)(b * S_ + q0 + w * 16 + lm)) * H_ + hoff;
  bf16x8 qf0 = *(const bf16x8*)(qrow + lq * 8);
  bf16x8 qf1 = *(const bf16x8*)(qrow + 32 + lq * 8);

  float m_ = -INFINITY, l_ = 0.f;
  f32x4 o[4];
#pragma unroll
  for (int i = 0; i < 4; ++i) o[i] = (f32x4){0.f, 0.f, 0.f, 0.f};

  // staging: 512 16B-chunks per tensor; thread handles chunks tid, tid+256
  int r0 = tid >> 3, c0 = (tid & 7) * 8;  // rows 0..31, then +32
  const short* kg = kb + ((size_t)(b * S_)) * H_ + hoff;
  const short* vg = vtb + ((size_t)(b * H_ + hoff)) * S_;
  const float C1 = 0.1803368802f;  // 0.125 * log2(e)

  // prefetch tile 0
  bf16x8 kv0 = *(const bf16x8*)(kg + (size_t)r0 * H_ + c0);
  bf16x8 kv1 = *(const bf16x8*)(kg + (size_t)(r0 + 32) * H_ + c0);
  bf16x8 vv0 = *(const bf16x8*)(vg + (size_t)r0 * S_ + c0);
  bf16x8 vv1 = *(const bf16x8*)(vg + (size_t)(r0 + 32) * S_ + c0);

  for (int kt = 0; kt < S_; kt += 64) {
    __syncthreads();  // prev tile frag reads done
    *(bf16x8*)&Ks[r0 * 72 + c0] = kv0;
    *(bf16x8*)&Ks[(r0 + 32) * 72 + c0] = kv1;
    *(bf16x8*)&Vt[r0 * 72 + c0] = vv0;
    *(bf16x8*)&Vt[(r0 + 32) * 72 + c0] = vv1;
    __syncthreads();
    if (kt + 64 < S_) {  // prefetch next tile (overlaps compute)
      int k2 = kt + 64;
      kv0 = *(const bf16x8*)(kg + (size_t)(k2 + r0) * H_ + c0);
      kv1 = *(const bf16x8*)(kg + (size_t)(k2 + r0 + 32) * H_ + c0);
      vv0 = *(const bf16x8*)(vg + (size_t)r0 * S_ + k2 + c0);
      vv1 = *(const bf16x8*)(vg + (size_t)(r0 + 32) * S_ + k2 + c0);
    }

    // ---- S^T[sk][q]: sk = ni*16 + lq*4 + r, q = lm ----
    f32x4 st[4];
#pragma unroll
    for (int ni = 0; ni < 4; ++ni) {
      bf16x8 ka0 = *(const bf16x8*)&Ks[(ni * 16 + lm) * 72 + lq * 8];
      bf16x8 ka1 = *(const bf16x8*)&Ks[(ni * 16 + lm) * 72 + 32 + lq * 8];
      f32x4 z = (f32x4){0.f, 0.f, 0.f, 0.f};
      z = __builtin_amdgcn_mfma_f32_16x16x32_bf16(ka0, qf0, z, 0, 0, 0);
      st[ni] = __builtin_amdgcn_mfma_f32_16x16x32_bf16(ka1, qf1, z, 0, 0, 0);
    }

    // ---- per-lane online softmax (q = lm; scale folded into exp2) ----
    float mx = st[0][0];
#pragma unroll
    for (int ni = 0; ni < 4; ++ni)
#pragma unroll
      for (int r = 0; r < 4; ++r) mx = fmaxf(mx, st[ni][r]);
    mx = fmaxf(mx, __shfl_xor(mx, 16));
    mx = fmaxf(mx, __shfl_xor(mx, 32));
    float mnew = fmaxf(m_, mx);
    float al = exp2f((m_ - mnew) * C1);
    float t = mnew * C1;
    float rs = 0.f;
    float pp[4][4];
#pragma unroll
    for (int ni = 0; ni < 4; ++ni)
#pragma unroll
      for (int r = 0; r < 4; ++r) {
        float p = exp2f(st[ni][r] * C1 - t);
        pp[ni][r] = p;
        rs += p;
      }
#pragma unroll
    for (int ni = 0; ni < 4; ++ni) {
      s16x4 pk = {f2bf(pp[ni][0]), f2bf(pp[ni][1]), f2bf(pp[ni][2]), f2bf(pp[ni][3])};
      *(s16x4*)&Ps[(w * 16 + lm) * 72 + ni * 16 + lq * 4] = pk;  // wave-private
    }
    rs += __shfl_xor(rs, 16);
    rs += __shfl_xor(rs, 32);
    l_ = l_ * al + rs;
    m_ = mnew;
#pragma unroll
    for (int nd = 0; nd < 4; ++nd) o[nd] *= al;

    // ---- O^T += V^T P^T ----
    bf16x8 pf0 = *(const bf16x8*)&Ps[(w * 16 + lm) * 72 + lq * 8];
    bf16x8 pf1 = *(const bf16x8*)&Ps[(w * 16 + lm) * 72 + 32 + lq * 8];
#pragma unroll
    for (int nd = 0; nd < 4; ++nd) {
      bf16x8 va0 = *(const bf16x8*)&Vt[(nd * 16 + lm) * 72 + lq * 8];
      bf16x8 va1 = *(const bf16x8*)&Vt[(nd * 16 + lm) * 72 + 32 + lq * 8];
      o[nd] = __builtin_amdgcn_mfma_f32_16x16x32_bf16(va0, pf0, o[nd], 0, 0, 0);
      o[nd] = __builtin_amdgcn_mfma_f32_16x16x32_bf16(va1, pf1, o[nd], 0, 0, 0);
    }
  }

  // epilogue: lane q = lm; d = nd*16 + lq*4 + r -> packed b64 bf16 stores
  float inv = 1.0f / l_;
  short* orow = aob + ((size_t)(b * S_ + q0 + w * 16 + lm)) * H_ + hoff;
#pragma unroll
  for (int nd = 0; nd < 4; ++nd) {
    s16x4 pk = {f2bf(o[nd][0] * inv), f2bf(o[nd][1] * inv),
                f2bf(o[nd][2] * inv), f2bf(o[nd][3] * inv)};
    *(s16x4*)(orow + nd * 16 + lq * 4) = pk;
  }
}

// ---------------------------------------------------------------------------
// gate + masked residual + aux partials (x fp32; br/inj bf16)
// ---------------------------------------------------------------------------
__global__ __launch_bounds__(256) void gate_out_k(const float* __restrict__ x,
                                                  const short* __restrict__ br,
                                                  const short* __restrict__ inj,
                                                  const int* __restrict__ mask,
                                                  const float* __restrict__ Wg,
                                                  const float* __restrict__ bg,
                                                  float* __restrict__ out,
                                                  float* __restrict__ paux) {
  int row = blockIdx.x;
  int b = row >> 11;
  size_t base = (size_t)row * H_;
  float dot = 0.f, aux = 0.f;
  for (int h = threadIdx.x; h < H_; h += 256) {
    float xv = x[base + h], bv = bf2f(br[base + h]);
    dot += xv * Wg[h] + bv * Wg[H_ + h];
    float d = bv - xv;
    aux += d * d;
  }
  for (int off = 32; off > 0; off >>= 1) {
    dot += __shfl_down(dot, off);
    aux += __shfl_down(aux, off);
  }
  __shared__ float sd[4], sx[4], gsh[2];
  int wid = threadIdx.x >> 6, lane = threadIdx.x & 63;
  if (lane == 0) { sd[wid] = dot; sx[wid] = aux; }
  __syncthreads();
  if (threadIdx.x == 0) {
    float td = sd[0] + sd[1] + sd[2] + sd[3];
    float ta = sx[0] + sx[1] + sx[2] + sx[3];
    gsh[0] = 1.0f / (1.0f + expf(-(td + bg[0])));
    gsh[1] = ta;
  }
  __syncthreads();
  float mf = (mask[b] != 0) ? 1.0f : 0.0f;
  float gm = gsh[0] * mf;
  for (int h = threadIdx.x; h < H_; h += 256)
    out[base + h] = x[base + h] + gm * tanhf(bf2f(inj[base + h]));
  if (threadIdx.x == 0) paux[row] = mf * gsh[1];
}

__global__ __launch_bounds__(256) void aux_reduce_k(const float* __restrict__ paux,
                                                    const int* __restrict__ mask,
                                                    float* __restrict__ outp) {
  float s = 0.f;
  for (int i = threadIdx.x; i < NROWS; i += 256) s += paux[i];
  for (int off = 32; off > 0; off >>= 1) s += __shfl_down(s, off);
  __shared__ float sw[4];
  int wid = threadIdx.x >> 6, lane = threadIdx.x & 63;
  if (lane == 0) sw[wid] = s;
  __syncthreads();
  if (threadIdx.x == 0) {
    float t = sw[0] + sw[1] + sw[2] + sw[3];
    int nm = (mask[0] != 0) + (mask[1] != 0) + (mask[2] != 0) + (mask[3] != 0);
    if (nm < 1) nm = 1;
    outp[0] = t / ((float)nm * (float)(S_ * H_));
  }
}

// ---------------------------------------------------------------------------
extern "C" void kernel_launch(void* const* d_in, const int* in_sizes, int n_in,
                              void* d_out, int out_size, void* d_ws, size_t ws_size,
                              hipStream_t stream) {
  const float* x     = (const float*)d_in[0];
  const float* prev  = (const float*)d_in[1];
  const int*   mask  = (const int*)d_in[2];
  const float* dw_w  = (const float*)d_in[3];
  const float* dw_b  = (const float*)d_in[4];
  const float* pw_w  = (const float*)d_in[5];
  const float* pw_b  = (const float*)d_in[6];
  const float* cn_g  = (const float*)d_in[7];
  const float* cn_b  = (const float*)d_in[8];
  const float* Wq    = (const float*)d_in[9];
  const float* bq    = (const float*)d_in[10];
  const float* Wk    = (const float*)d_in[11];
  const float* bk    = (const float*)d_in[12];
  const float* Wv    = (const float*)d_in[13];
  const float* bv    = (const float*)d_in[14];
  const float* Wo    = (const float*)d_in[15];
  const float* bo    = (const float*)d_in[16];
  const float* pn_g  = (const float*)d_in[17];
  const float* pn_b  = (const float*)d_in[18];
  const float* Wpost = (const float*)d_in[19];
  const float* bpost = (const float*)d_in[20];
  const float* Wg    = (const float*)d_in[21];
  const float* bg    = (const float*)d_in[22];
  float* out = (float*)d_out;

  // workspace (bf16 activations): 6 x BSH shorts + 6 weights + paux  (~83 MB)
  short* B0 = (short*)d_ws;     // xb
  short* B1 = B0 + BSH;         // dwo -> qb
  short* B2 = B1 + BSH;         // gelu-out -> aob
  short* B3 = B2 + BSH;         // bridged (until gate)
  short* B4 = B3 + BSH;         // kb -> ao_proj -> pn
  short* B5 = B4 + BSH;         // vtb -> injb
  short* WW = B5 + BSH;         // 6 bf16 weights [pw,q,k,v,o,post]
  float* paux = (float*)(WW + 6 * WSZ);

  dim3 ggrid(H_ / 128, NROWS / 128);  // (6, 64)

  cvt6_k<<<6 * WSZ / 1024, 256, 0, stream>>>(pw_w, Wq, Wk, Wv, Wo, Wpost, WW);
  cvt_x_k<<<BSH / 1024, 256, 0, stream>>>(x, B0);
  dwconv_k<<<NROWS, 256, 0, stream>>>(prev, dw_w, dw_b, B1);
  gemm_bf<<<ggrid, 256, 0, stream>>>(B1, WW, pw_b, B2, 1, 0);              // pw + GELU
  ln_bf<<<NROWS, 256, 0, stream>>>(B2, B3, cn_g, cn_b);                    // bridged
  gemm_bf<<<ggrid, 256, 0, stream>>>(B0, WW + WSZ, bq, B1, 0, 0);          // q
  gemm_bf<<<ggrid, 256, 0, stream>>>(B3, WW + 2 * WSZ, bk, B4, 0, 0);      // k
  gemm_bf<<<ggrid, 256, 0, stream>>>(B3, WW + 3 * WSZ, bv, B5, 0, 1);      // v (transposed)
  attn2_k<<<dim3(S_ / 64, NH_, B_), 256, 0, stream>>>(B1, B4, B5, B2);     // -> aob
  gemm_bf<<<ggrid, 256, 0, stream>>>(B2, WW + 4 * WSZ, bo, B4, 0, 0);      // o-proj
  ln_bf<<<NROWS, 256, 0, stream>>>(B4, B4, pn_g, pn_b);                    // pn (in-place)
  gemm_bf<<<ggrid, 256, 0, stream>>>(B4, WW + 5 * WSZ, bpost, B5, 0, 0);   // post
  gate_out_k<<<NROWS, 256, 0, stream>>>(x, B3, B5, mask, Wg, bg, out, paux);
  aux_reduce_k<<<1, 256, 0, stream>>>(paux, mask, out + BSH);
}

// Round 4
// 438.644 us; speedup vs baseline: 4.4836x; 1.0687x over previous
//
#include <hip/hip_runtime.h>
#include <math.h>

#define B_ 4
#define S_ 2048
#define H_ 768
#define NH_ 12
#define HD_ 64
#define BSH (B_ * S_ * H_)
#define NROWS (B_ * S_)
#define WSZ (H_ * H_)  // 589824

typedef __attribute__((ext_vector_type(8))) short bf16x8;
typedef __attribute__((ext_vector_type(4))) short s16x4;
typedef __attribute__((ext_vector_type(4))) float f32x4;
typedef __attribute__((ext_vector_type(2))) unsigned u32x2;

__device__ __forceinline__ short f2bf(float f) {
  union { float f; unsigned u; } x; x.f = f;
  unsigned r = x.u + 0x7FFF + ((x.u >> 16) & 1);
  return (short)(r >> 16);
}
__device__ __forceinline__ float bf2f(short s) {
  union { unsigned u; float f; } x;
  x.u = ((unsigned)(unsigned short)s) << 16;
  return x.f;
}
// pack 2 fp32 -> 2 bf16 (truncation) in one v_perm_b32; lo in low short
__device__ __forceinline__ unsigned bfpack(float lo, float hi) {
  union { float f; unsigned u; } a, b; a.f = lo; b.f = hi;
  return __builtin_amdgcn_perm(b.u, a.u, 0x07060302);
}

// async global->LDS, 16B per lane
typedef __attribute__((address_space(1))) const unsigned int g_u32;
typedef __attribute__((address_space(3))) unsigned int l_u32;
__device__ __forceinline__ void gload16(const void* g, void* l) {
  __builtin_amdgcn_global_load_lds((g_u32*)g, (l_u32*)l, 16, 0, 0);
}

// ---------------------------------------------------------------------------
// fp32 -> bf16 converters
// ---------------------------------------------------------------------------
__global__ __launch_bounds__(256) void cvt_x_k(const float* __restrict__ src,
                                               short* __restrict__ dst) {
  int i = (blockIdx.x * 256 + threadIdx.x) * 4;
  float4 v = *(const float4*)(src + i);
  s16x4 o = {f2bf(v.x), f2bf(v.y), f2bf(v.z), f2bf(v.w)};
  *(s16x4*)(dst + i) = o;
}

__global__ __launch_bounds__(256) void cvt6_k(const float* w0, const float* w1,
                                              const float* w2, const float* w3,
                                              const float* w4, const float* w5,
                                              short* __restrict__ dst) {
  int i = (blockIdx.x * 256 + threadIdx.x) * 4;
  int m = i / WSZ;
  int off = i - m * WSZ;
  const float* s = m == 0 ? w0 : m == 1 ? w1 : m == 2 ? w2 : m == 3 ? w3 : m == 4 ? w4 : w5;
  float4 v = *(const float4*)(s + off);
  s16x4 o = {f2bf(v.x), f2bf(v.y), f2bf(v.z), f2bf(v.w)};
  *(s16x4*)(dst + i) = o;
}

// ---------------------------------------------------------------------------
// depthwise conv1d k=3 pad=1 over seq dim; [B,S,H] fp32 -> bf16
// ---------------------------------------------------------------------------
__global__ __launch_bounds__(256) void dwconv_k(const float* __restrict__ prev,
                                                const float* __restrict__ w3,
                                                const float* __restrict__ bias,
                                                short* __restrict__ out) {
  int row = blockIdx.x;
  int s = row & (S_ - 1);
  size_t base = (size_t)row * H_;
  for (int h = threadIdx.x; h < H_; h += 256) {
    float acc = bias[h] + prev[base + h] * w3[h * 3 + 1];
    if (s > 0)      acc += prev[base - H_ + h] * w3[h * 3 + 0];
    if (s < S_ - 1) acc += prev[base + H_ + h] * w3[h * 3 + 2];
    out[base + h] = f2bf(acc);
  }
}

// ---------------------------------------------------------------------------
// C[m,n] = sum_k A[m,k]*W[n,k] + bias[n]; bf16 in/out, fp32 accum.
// m97 structure: global_load_lds width=16, unpadded [128][32] bf16 tiles.
// ---------------------------------------------------------------------------
__global__ __launch_bounds__(256) void gemm_bf(const short* __restrict__ A,
                                               const short* __restrict__ W,
                                               const float* __restrict__ bias,
                                               short* __restrict__ C,
                                               int act, int tout) {
  __shared__ short As[4096];
  __shared__ short Ws[4096];
  int tid = threadIdx.x, lane = tid & 63, w = tid >> 6;
  int wr = w >> 1, wc = w & 1, lm = lane & 15, lq = lane >> 4;
  int m0 = blockIdx.y * 128, n0 = blockIdx.x * 128;
  int srow = w * 32 + (lane >> 2);
  int skc = (lane & 3) * 8;
  const short* gA = A + (size_t)(m0 + srow) * H_ + skc;
  const short* gW = W + (size_t)(n0 + srow) * H_ + skc;
  short* lA = As + w * 1024;
  short* lW = Ws + w * 1024;

  f32x4 acc[4][4];
#pragma unroll
  for (int i = 0; i < 4; ++i)
#pragma unroll
    for (int j = 0; j < 4; ++j) acc[i][j] = (f32x4){0.f, 0.f, 0.f, 0.f};

  for (int kt = 0; kt < H_; kt += 32) {
    __syncthreads();
    gload16(gA + kt, lA);
    gload16(gA + kt + 16 * H_, lA + 512);
    gload16(gW + kt, lW);
    gload16(gW + kt + 16 * H_, lW + 512);
    __syncthreads();
    bf16x8 af[4], wf[4];
#pragma unroll
    for (int i = 0; i < 4; ++i) af[i] = *(const bf16x8*)&As[(wr * 64 + i * 16 + lm) * 32 + lq * 8];
#pragma unroll
    for (int j = 0; j < 4; ++j) wf[j] = *(const bf16x8*)&Ws[(wc * 64 + j * 16 + lm) * 32 + lq * 8];
#pragma unroll
    for (int i = 0; i < 4; ++i)
#pragma unroll
      for (int j = 0; j < 4; ++j)
        acc[i][j] = __builtin_amdgcn_mfma_f32_16x16x32_bf16(af[i], wf[j], acc[i][j], 0, 0, 0);
  }

  if (!tout) {
#pragma unroll
    for (int j = 0; j < 4; ++j) {
      int col = n0 + wc * 64 + j * 16 + lm;
      float bn = bias[col];
#pragma unroll
      for (int i = 0; i < 4; ++i) {
        int mrow = m0 + wr * 64 + i * 16 + lq * 4;
#pragma unroll
        for (int r = 0; r < 4; ++r) {
          float cv = acc[i][j][r] + bn;
          if (act) cv = 0.5f * cv * (1.0f + erff(cv * 0.70710678118f));
          C[(size_t)(mrow + r) * H_ + col] = f2bf(cv);
        }
      }
    }
  } else {
    int b = m0 >> 11;
    int sb = (m0 & (S_ - 1)) + wr * 64;
#pragma unroll
    for (int j = 0; j < 4; ++j) {
      int col = n0 + wc * 64 + j * 16 + lm;
      float bn = bias[col];
      short* cp = C + ((size_t)(b * H_ + col)) * S_;
#pragma unroll
      for (int i = 0; i < 4; ++i) {
        int s = sb + i * 16 + lq * 4;
        s16x4 pk = {f2bf(acc[i][j][0] + bn), f2bf(acc[i][j][1] + bn),
                    f2bf(acc[i][j][2] + bn), f2bf(acc[i][j][3] + bn)};
        *(s16x4*)(cp + s) = pk;
      }
    }
  }
}

// ---------------------------------------------------------------------------
// LayerNorm over last dim (H=768), bf16 in -> bf16 out
// ---------------------------------------------------------------------------
__global__ __launch_bounds__(256) void ln_bf(const short* __restrict__ X,
                                             short* __restrict__ Y,
                                             const float* __restrict__ g,
                                             const float* __restrict__ bb) {
  int row = blockIdx.x;
  size_t base = (size_t)row * H_;
  int h0 = threadIdx.x, h1 = h0 + 256, h2 = h0 + 512;
  float x0 = bf2f(X[base + h0]), x1 = bf2f(X[base + h1]), x2 = bf2f(X[base + h2]);
  float s = x0 + x1 + x2;
  float s2 = x0 * x0 + x1 * x1 + x2 * x2;
  for (int off = 32; off > 0; off >>= 1) {
    s += __shfl_down(s, off);
    s2 += __shfl_down(s2, off);
  }
  __shared__ float sa[4], sq[4], st[2];
  int wid = threadIdx.x >> 6, lane = threadIdx.x & 63;
  if (lane == 0) { sa[wid] = s; sq[wid] = s2; }
  __syncthreads();
  if (threadIdx.x == 0) {
    float ts = sa[0] + sa[1] + sa[2] + sa[3];
    float ts2 = sq[0] + sq[1] + sq[2] + sq[3];
    float mean = ts * (1.0f / H_);
    float var = ts2 * (1.0f / H_) - mean * mean;
    st[0] = mean;
    st[1] = rsqrtf(var + 1e-5f);
  }
  __syncthreads();
  float mean = st[0], rstd = st[1];
  Y[base + h0] = f2bf((x0 - mean) * rstd * g[h0] + bb[h0]);
  Y[base + h1] = f2bf((x1 - mean) * rstd * g[h1] + bb[h1]);
  Y[base + h2] = f2bf((x2 - mean) * rstd * g[h2] + bb[h2]);
}

// ---------------------------------------------------------------------------
// Swapped-orientation MFMA flash attention, 512 threads = 8 waves, 128 q/block.
// No online max (scores provably small: exp2 overflow needs |s|~700);
// softmax shift-invariance keeps the result exact.
// S^T = K Q^T; O^T = V^T P^T with Ps[q][sk] serving as the PV B-operand.
// ---------------------------------------------------------------------------
__global__ __launch_bounds__(512) void attn3_k(const short* __restrict__ qb,
                                               const short* __restrict__ kb,
                                               const short* __restrict__ vtb,
                                               short* __restrict__ aob) {
  __shared__ short Ks[64 * 72];       // [sk][d]
  __shared__ short Vt[64 * 72];       // [d][sk]
  __shared__ short Ps[8 * 16 * 72];   // per-wave [q16][sk64]
  int tid = threadIdx.x, lane = tid & 63, w = tid >> 6;  // w 0..7
  int lm = lane & 15, lq = lane >> 4;
  int b = blockIdx.z, n = blockIdx.y, q0 = blockIdx.x * 128;
  int hoff = n * HD_;

  const short* qrow = qb + ((size_t)(b * S_ + q0 + w * 16 + lm)) * H_ + hoff;
  bf16x8 qf0 = *(const bf16x8*)(qrow + lq * 8);
  bf16x8 qf1 = *(const bf16x8*)(qrow + 32 + lq * 8);

  float l_ = 0.f;
  f32x4 o[4];
#pragma unroll
  for (int i = 0; i < 4; ++i) o[i] = (f32x4){0.f, 0.f, 0.f, 0.f};

  int r0 = tid >> 3, c0 = (tid & 7) * 8;  // 512 thr: 1 chunk each of K and V
  const short* kg = kb + ((size_t)(b * S_)) * H_ + hoff;
  const short* vg = vtb + ((size_t)(b * H_ + hoff)) * S_;
  const float C1 = 0.1803368802f;  // 0.125 * log2(e)

  bf16x8 kv = *(const bf16x8*)(kg + (size_t)r0 * H_ + c0);
  bf16x8 vv = *(const bf16x8*)(vg + (size_t)r0 * S_ + c0);

  for (int kt = 0; kt < S_; kt += 64) {
    __syncthreads();
    *(bf16x8*)&Ks[r0 * 72 + c0] = kv;
    *(bf16x8*)&Vt[r0 * 72 + c0] = vv;
    __syncthreads();
    if (kt + 64 < S_) {
      kv = *(const bf16x8*)(kg + (size_t)(kt + 64 + r0) * H_ + c0);
      vv = *(const bf16x8*)(vg + (size_t)r0 * S_ + kt + 64 + c0);
    }

    // ---- S^T[sk][q]: sk = ni*16 + lq*4 + r, q = lm ----
    f32x4 st[4];
#pragma unroll
    for (int ni = 0; ni < 4; ++ni) {
      bf16x8 ka0 = *(const bf16x8*)&Ks[(ni * 16 + lm) * 72 + lq * 8];
      bf16x8 ka1 = *(const bf16x8*)&Ks[(ni * 16 + lm) * 72 + 32 + lq * 8];
      f32x4 z = (f32x4){0.f, 0.f, 0.f, 0.f};
      z = __builtin_amdgcn_mfma_f32_16x16x32_bf16(ka0, qf0, z, 0, 0, 0);
      st[ni] = __builtin_amdgcn_mfma_f32_16x16x32_bf16(ka1, qf1, z, 0, 0, 0);
    }

    // ---- softmax numerator (no max shift) + P pack via v_perm ----
    float rs = 0.f;
#pragma unroll
    for (int ni = 0; ni < 4; ++ni) {
      float p0 = exp2f(st[ni][0] * C1);
      float p1 = exp2f(st[ni][1] * C1);
      float p2 = exp2f(st[ni][2] * C1);
      float p3 = exp2f(st[ni][3] * C1);
      rs += (p0 + p1) + (p2 + p3);
      u32x2 pk = {bfpack(p0, p1), bfpack(p2, p3)};
      *(u32x2*)&Ps[(w * 16 + lm) * 72 + ni * 16 + lq * 4] = pk;
    }
    rs += __shfl_xor(rs, 16);
    rs += __shfl_xor(rs, 32);
    l_ += rs;

    // ---- O^T += V^T P^T ----
    bf16x8 pf0 = *(const bf16x8*)&Ps[(w * 16 + lm) * 72 + lq * 8];
    bf16x8 pf1 = *(const bf16x8*)&Ps[(w * 16 + lm) * 72 + 32 + lq * 8];
#pragma unroll
    for (int nd = 0; nd < 4; ++nd) {
      bf16x8 va0 = *(const bf16x8*)&Vt[(nd * 16 + lm) * 72 + lq * 8];
      bf16x8 va1 = *(const bf16x8*)&Vt[(nd * 16 + lm) * 72 + 32 + lq * 8];
      o[nd] = __builtin_amdgcn_mfma_f32_16x16x32_bf16(va0, pf0, o[nd], 0, 0, 0);
      o[nd] = __builtin_amdgcn_mfma_f32_16x16x32_bf16(va1, pf1, o[nd], 0, 0, 0);
    }
  }

  float inv = 1.0f / l_;
  short* orow = aob + ((size_t)(b * S_ + q0 + w * 16 + lm)) * H_ + hoff;
#pragma unroll
  for (int nd = 0; nd < 4; ++nd) {
    s16x4 pk = {f2bf(o[nd][0] * inv), f2bf(o[nd][1] * inv),
                f2bf(o[nd][2] * inv), f2bf(o[nd][3] * inv)};
    *(s16x4*)(orow + nd * 16 + lq * 4) = pk;
  }
}

// ---------------------------------------------------------------------------
// gate + masked residual + aux partials (x fp32; br/inj bf16)
// ---------------------------------------------------------------------------
__global__ __launch_bounds__(256) void gate_out_k(const float* __restrict__ x,
                                                  const short* __restrict__ br,
                                                  const short* __restrict__ inj,
                                                  const int* __restrict__ mask,
                                                  const float* __restrict__ Wg,
                                                  const float* __restrict__ bg,
                                                  float* __restrict__ out,
                                                  float* __restrict__ paux) {
  int row = blockIdx.x;
  int b = row >> 11;
  size_t base = (size_t)row * H_;
  float dot = 0.f, aux = 0.f;
  for (int h = threadIdx.x; h < H_; h += 256) {
    float xv = x[base + h], bv = bf2f(br[base + h]);
    dot += xv * Wg[h] + bv * Wg[H_ + h];
    float d = bv - xv;
    aux += d * d;
  }
  for (int off = 32; off > 0; off >>= 1) {
    dot += __shfl_down(dot, off);
    aux += __shfl_down(aux, off);
  }
  __shared__ float sd[4], sx[4], gsh[2];
  int wid = threadIdx.x >> 6, lane = threadIdx.x & 63;
  if (lane == 0) { sd[wid] = dot; sx[wid] = aux; }
  __syncthreads();
  if (threadIdx.x == 0) {
    float td = sd[0] + sd[1] + sd[2] + sd[3];
    float ta = sx[0] + sx[1] + sx[2] + sx[3];
    gsh[0] = 1.0f / (1.0f + expf(-(td + bg[0])));
    gsh[1] = ta;
  }
  __syncthreads();
  float mf = (mask[b] != 0) ? 1.0f : 0.0f;
  float gm = gsh[0] * mf;
  for (int h = threadIdx.x; h < H_; h += 256) {
    float v = bf2f(inj[base + h]);
    float e = __expf(2.0f * v);            // fast tanh: (e-1)/(e+1)
    float th = (e - 1.0f) / (e + 1.0f);
    out[base + h] = x[base + h] + gm * th;
  }
  if (threadIdx.x == 0) paux[row] = mf * gsh[1];
}

__global__ __launch_bounds__(256) void aux_reduce_k(const float* __restrict__ paux,
                                                    const int* __restrict__ mask,
                                                    float* __restrict__ outp) {
  float s = 0.f;
  for (int i = threadIdx.x; i < NROWS; i += 256) s += paux[i];
  for (int off = 32; off > 0; off >>= 1) s += __shfl_down(s, off);
  __shared__ float sw[4];
  int wid = threadIdx.x >> 6, lane = threadIdx.x & 63;
  if (lane == 0) sw[wid] = s;
  __syncthreads();
  if (threadIdx.x == 0) {
    float t = sw[0] + sw[1] + sw[2] + sw[3];
    int nm = (mask[0] != 0) + (mask[1] != 0) + (mask[2] != 0) + (mask[3] != 0);
    if (nm < 1) nm = 1;
    outp[0] = t / ((float)nm * (float)(S_ * H_));
  }
}

// ---------------------------------------------------------------------------
extern "C" void kernel_launch(void* const* d_in, const int* in_sizes, int n_in,
                              void* d_out, int out_size, void* d_ws, size_t ws_size,
                              hipStream_t stream) {
  const float* x     = (const float*)d_in[0];
  const float* prev  = (const float*)d_in[1];
  const int*   mask  = (const int*)d_in[2];
  const float* dw_w  = (const float*)d_in[3];
  const float* dw_b  = (const float*)d_in[4];
  const float* pw_w  = (const float*)d_in[5];
  const float* pw_b  = (const float*)d_in[6];
  const float* cn_g  = (const float*)d_in[7];
  const float* cn_b  = (const float*)d_in[8];
  const float* Wq    = (const float*)d_in[9];
  const float* bq    = (const float*)d_in[10];
  const float* Wk    = (const float*)d_in[11];
  const float* bk    = (const float*)d_in[12];
  const float* Wv    = (const float*)d_in[13];
  const float* bv    = (const float*)d_in[14];
  const float* Wo    = (const float*)d_in[15];
  const float* bo    = (const float*)d_in[16];
  const float* pn_g  = (const float*)d_in[17];
  const float* pn_b  = (const float*)d_in[18];
  const float* Wpost = (const float*)d_in[19];
  const float* bpost = (const float*)d_in[20];
  const float* Wg    = (const float*)d_in[21];
  const float* bg    = (const float*)d_in[22];
  float* out = (float*)d_out;

  short* B0 = (short*)d_ws;     // xb
  short* B1 = B0 + BSH;         // dwo -> qb
  short* B2 = B1 + BSH;         // gelu-out -> aob
  short* B3 = B2 + BSH;         // bridged (until gate)
  short* B4 = B3 + BSH;         // kb -> ao_proj -> pn
  short* B5 = B4 + BSH;         // vtb -> injb
  short* WW = B5 + BSH;         // 6 bf16 weights [pw,q,k,v,o,post]
  float* paux = (float*)(WW + 6 * WSZ);

  dim3 ggrid(H_ / 128, NROWS / 128);  // (6, 64)

  cvt6_k<<<6 * WSZ / 1024, 256, 0, stream>>>(pw_w, Wq, Wk, Wv, Wo, Wpost, WW);
  cvt_x_k<<<BSH / 1024, 256, 0, stream>>>(x, B0);
  dwconv_k<<<NROWS, 256, 0, stream>>>(prev, dw_w, dw_b, B1);
  gemm_bf<<<ggrid, 256, 0, stream>>>(B1, WW, pw_b, B2, 1, 0);              // pw + GELU
  ln_bf<<<NROWS, 256, 0, stream>>>(B2, B3, cn_g, cn_b);                    // bridged
  gemm_bf<<<ggrid, 256, 0, stream>>>(B0, WW + WSZ, bq, B1, 0, 0);          // q
  gemm_bf<<<ggrid, 256, 0, stream>>>(B3, WW + 2 * WSZ, bk, B4, 0, 0);      // k
  gemm_bf<<<ggrid, 256, 0, stream>>>(B3, WW + 3 * WSZ, bv, B5, 0, 1);      // v (transposed)
  attn3_k<<<dim3(S_ / 128, NH_, B_), 512, 0, stream>>>(B1, B4, B5, B2);    // -> aob
  gemm_bf<<<ggrid, 256, 0, stream>>>(B2, WW + 4 * WSZ, bo, B4, 0, 0);      // o-proj
  ln_bf<<<NROWS, 256, 0, stream>>>(B4, B4, pn_g, pn_b);                    // pn
  gemm_bf<<<ggrid, 256, 0, stream>>>(B4, WW + 5 * WSZ, bpost, B5, 0, 0);   // post
  gate_out_k<<<NROWS, 256, 0, stream>>>(x, B3, B5, mask, Wg, bg, out, paux);
  aux_reduce_k<<<1, 256, 0, stream>>>(paux, mask, out + BSH);
}

// Round 5
// 419.241 us; speedup vs baseline: 4.6911x; 1.0463x over previous
//
#include <hip/hip_runtime.h>
#include <math.h>

#define B_ 4
#define S_ 2048
#define H_ 768
#define NH_ 12
#define HD_ 64
#define BSH (B_ * S_ * H_)
#define NROWS (B_ * S_)
#define WSZ (H_ * H_)  // 589824

typedef __attribute__((ext_vector_type(8))) short bf16x8;
typedef __attribute__((ext_vector_type(4))) short s16x4;
typedef __attribute__((ext_vector_type(4))) float f32x4;
typedef __attribute__((ext_vector_type(2))) unsigned u32x2;

__device__ __forceinline__ short f2bf(float f) {
  union { float f; unsigned u; } x; x.f = f;
  unsigned r = x.u + 0x7FFF + ((x.u >> 16) & 1);
  return (short)(r >> 16);
}
__device__ __forceinline__ float bf2f(short s) {
  union { unsigned u; float f; } x;
  x.u = ((unsigned)(unsigned short)s) << 16;
  return x.f;
}
// pack 2 fp32 -> 2 bf16 (truncation) in one v_perm_b32
__device__ __forceinline__ unsigned bfpack(float lo, float hi) {
  union { float f; unsigned u; } a, b; a.f = lo; b.f = hi;
  return __builtin_amdgcn_perm(b.u, a.u, 0x07060302);
}

// async global->LDS, 16B per lane; LDS dst = wave-uniform base + lane*16
typedef __attribute__((address_space(1))) const unsigned int g_u32;
typedef __attribute__((address_space(3))) unsigned int l_u32;
__device__ __forceinline__ void gload16(const void* g, void* l) {
  __builtin_amdgcn_global_load_lds((g_u32*)g, (l_u32*)l, 16, 0, 0);
}

// ---------------------------------------------------------------------------
// fp32 -> bf16 converters
// ---------------------------------------------------------------------------
__global__ __launch_bounds__(256) void cvt_x_k(const float* __restrict__ src,
                                               short* __restrict__ dst) {
  int i = (blockIdx.x * 256 + threadIdx.x) * 4;
  float4 v = *(const float4*)(src + i);
  s16x4 o = {f2bf(v.x), f2bf(v.y), f2bf(v.z), f2bf(v.w)};
  *(s16x4*)(dst + i) = o;
}

__global__ __launch_bounds__(256) void cvt6_k(const float* w0, const float* w1,
                                              const float* w2, const float* w3,
                                              const float* w4, const float* w5,
                                              short* __restrict__ dst) {
  int i = (blockIdx.x * 256 + threadIdx.x) * 4;
  int m = i / WSZ;
  int off = i - m * WSZ;
  const float* s = m == 0 ? w0 : m == 1 ? w1 : m == 2 ? w2 : m == 3 ? w3 : m == 4 ? w4 : w5;
  float4 v = *(const float4*)(s + off);
  s16x4 o = {f2bf(v.x), f2bf(v.y), f2bf(v.z), f2bf(v.w)};
  *(s16x4*)(dst + i) = o;
}

// ---------------------------------------------------------------------------
// depthwise conv1d k=3 pad=1 over seq; vectorized x4, 192 thr (H/4=192)
// ---------------------------------------------------------------------------
__global__ __launch_bounds__(192) void dwconv_k(const float* __restrict__ prev,
                                                const float* __restrict__ w3,
                                                const float* __restrict__ bias,
                                                short* __restrict__ out) {
  int row = blockIdx.x;
  int s = row & (S_ - 1);
  int h = threadIdx.x * 4;
  size_t base = (size_t)row * H_ + h;
  float4 c = *(const float4*)(prev + base);
  float4 wa = *(const float4*)(w3 + h * 3);      // w(h,0..2), w(h+1,0)
  float4 wb = *(const float4*)(w3 + h * 3 + 4);  // w(h+1,1..2), w(h+2,0..1)
  float4 wc = *(const float4*)(w3 + h * 3 + 8);  // w(h+2,2), w(h+3,0..2)
  float4 bi = *(const float4*)(bias + h);
  float4 acc;
  acc.x = bi.x + c.x * wa.y;
  acc.y = bi.y + c.y * wb.x;
  acc.z = bi.z + c.z * wb.w;
  acc.w = bi.w + c.w * wc.z;
  if (s > 0) {
    float4 l = *(const float4*)(prev + base - H_);
    acc.x += l.x * wa.x; acc.y += l.y * wa.w; acc.z += l.z * wb.z; acc.w += l.w * wc.y;
  }
  if (s < S_ - 1) {
    float4 r = *(const float4*)(prev + base + H_);
    acc.x += r.x * wa.z; acc.y += r.y * wb.y; acc.z += r.z * wc.x; acc.w += r.w * wc.w;
  }
  s16x4 o = {f2bf(acc.x), f2bf(acc.y), f2bf(acc.z), f2bf(acc.w)};
  *(s16x4*)(out + base) = o;
}

// ---------------------------------------------------------------------------
// Grouped GEMM: C[m,n] = sum_k A[m,k]*W[n,k] + bias[n]; bf16 in/out, fp32 acc.
// BK=64 (12 iters), global_load_lds width=16, unpadded [128][64] tiles,
// 16x16x32 MFMA, 4 waves x 4x4 accs. blockIdx.z selects the job.
// ---------------------------------------------------------------------------
struct GemmJob {
  const short* A; const short* W; const float* bias; short* C; int act; int tout;
};

__global__ __launch_bounds__(256) void gemm_bf2(GemmJob j0, GemmJob j1, GemmJob j2) {
  GemmJob j = blockIdx.z == 0 ? j0 : (blockIdx.z == 1 ? j1 : j2);
  __shared__ short As[128 * 64];  // 16 KB
  __shared__ short Ws[128 * 64];
  int tid = threadIdx.x, lane = tid & 63, w = tid >> 6;
  int wr = w >> 1, wc = w & 1, lm = lane & 15, lq = lane >> 4;
  int m0 = blockIdx.y * 128, n0 = blockIdx.x * 128;
  // staging: call c covers rows w*32+c*8+(lane>>3), k-chunk (lane&7)*8
  int srow = lane >> 3;
  int skc = (lane & 7) * 8;
  const short* gA = j.A + (size_t)(m0 + w * 32 + srow) * H_ + skc;
  const short* gW = j.W + (size_t)(n0 + w * 32 + srow) * H_ + skc;
  short* lA = As + w * 2048;
  short* lW = Ws + w * 2048;

  f32x4 acc[4][4];
#pragma unroll
  for (int i = 0; i < 4; ++i)
#pragma unroll
    for (int jj = 0; jj < 4; ++jj) acc[i][jj] = (f32x4){0.f, 0.f, 0.f, 0.f};

  for (int kt = 0; kt < H_; kt += 64) {
    __syncthreads();  // prev frag reads done
#pragma unroll
    for (int c = 0; c < 4; ++c) {
      gload16(gA + kt + (size_t)(c * 8) * H_, lA + c * 512);
      gload16(gW + kt + (size_t)(c * 8) * H_, lW + c * 512);
    }
    __syncthreads();  // drains vmcnt: tiles ready
#pragma unroll
    for (int kk = 0; kk < 2; ++kk) {
      bf16x8 af[4], wf[4];
#pragma unroll
      for (int i = 0; i < 4; ++i)
        af[i] = *(const bf16x8*)&As[(wr * 64 + i * 16 + lm) * 64 + kk * 32 + lq * 8];
#pragma unroll
      for (int jj = 0; jj < 4; ++jj)
        wf[jj] = *(const bf16x8*)&Ws[(wc * 64 + jj * 16 + lm) * 64 + kk * 32 + lq * 8];
#pragma unroll
      for (int i = 0; i < 4; ++i)
#pragma unroll
        for (int jj = 0; jj < 4; ++jj)
          acc[i][jj] = __builtin_amdgcn_mfma_f32_16x16x32_bf16(af[i], wf[jj], acc[i][jj], 0, 0, 0);
    }
  }

  if (!j.tout) {
#pragma unroll
    for (int jj = 0; jj < 4; ++jj) {
      int col = n0 + wc * 64 + jj * 16 + lm;
      float bn = j.bias[col];
#pragma unroll
      for (int i = 0; i < 4; ++i) {
        int mrow = m0 + wr * 64 + i * 16 + lq * 4;
#pragma unroll
        for (int r = 0; r < 4; ++r) {
          float cv = acc[i][jj][r] + bn;
          if (j.act) cv = 0.5f * cv * (1.0f + erff(cv * 0.70710678118f));
          j.C[(size_t)(mrow + r) * H_ + col] = f2bf(cv);
        }
      }
    }
  } else {
    // transposed out: dst[b*H + col][s]; 4 C-rows = 4 consecutive s -> b64
    int b = m0 >> 11;
    int sb = (m0 & (S_ - 1)) + wr * 64;
#pragma unroll
    for (int jj = 0; jj < 4; ++jj) {
      int col = n0 + wc * 64 + jj * 16 + lm;
      float bn = j.bias[col];
      short* cp = j.C + ((size_t)(b * H_ + col)) * S_;
#pragma unroll
      for (int i = 0; i < 4; ++i) {
        int s = sb + i * 16 + lq * 4;
        s16x4 pk = {f2bf(acc[i][jj][0] + bn), f2bf(acc[i][jj][1] + bn),
                    f2bf(acc[i][jj][2] + bn), f2bf(acc[i][jj][3] + bn)};
        *(s16x4*)(cp + s) = pk;
      }
    }
  }
}

// ---------------------------------------------------------------------------
// LayerNorm over last dim (H=768), bf16 in -> bf16 out
// ---------------------------------------------------------------------------
__global__ __launch_bounds__(256) void ln_bf(const short* __restrict__ X,
                                             short* __restrict__ Y,
                                             const float* __restrict__ g,
                                             const float* __restrict__ bb) {
  int row = blockIdx.x;
  size_t base = (size_t)row * H_;
  int h0 = threadIdx.x, h1 = h0 + 256, h2 = h0 + 512;
  float x0 = bf2f(X[base + h0]), x1 = bf2f(X[base + h1]), x2 = bf2f(X[base + h2]);
  float s = x0 + x1 + x2;
  float s2 = x0 * x0 + x1 * x1 + x2 * x2;
  for (int off = 32; off > 0; off >>= 1) {
    s += __shfl_down(s, off);
    s2 += __shfl_down(s2, off);
  }
  __shared__ float sa[4], sq[4], st[2];
  int wid = threadIdx.x >> 6, lane = threadIdx.x & 63;
  if (lane == 0) { sa[wid] = s; sq[wid] = s2; }
  __syncthreads();
  if (threadIdx.x == 0) {
    float ts = sa[0] + sa[1] + sa[2] + sa[3];
    float ts2 = sq[0] + sq[1] + sq[2] + sq[3];
    float mean = ts * (1.0f / H_);
    float var = ts2 * (1.0f / H_) - mean * mean;
    st[0] = mean;
    st[1] = rsqrtf(var + 1e-5f);
  }
  __syncthreads();
  float mean = st[0], rstd = st[1];
  Y[base + h0] = f2bf((x0 - mean) * rstd * g[h0] + bb[h0]);
  Y[base + h1] = f2bf((x1 - mean) * rstd * g[h1] + bb[h1]);
  Y[base + h2] = f2bf((x2 - mean) * rstd * g[h2] + bb[h2]);
}

// ---------------------------------------------------------------------------
// Swapped-orientation MFMA flash attention, 512 threads = 8 waves, 128 q/block.
// No online max (scores bounded; softmax shift-invariant -> exact).
// S^T = K Q^T; O^T = V^T P^T with Ps[q][sk] serving as the PV B-operand.
// ---------------------------------------------------------------------------
__global__ __launch_bounds__(512) void attn3_k(const short* __restrict__ qb,
                                               const short* __restrict__ kb,
                                               const short* __restrict__ vtb,
                                               short* __restrict__ aob) {
  __shared__ short Ks[64 * 72];       // [sk][d]
  __shared__ short Vt[64 * 72];       // [d][sk]
  __shared__ short Ps[8 * 16 * 72];   // per-wave [q16][sk64]
  int tid = threadIdx.x, lane = tid & 63, w = tid >> 6;  // w 0..7
  int lm = lane & 15, lq = lane >> 4;
  int b = blockIdx.z, n = blockIdx.y, q0 = blockIdx.x * 128;
  int hoff = n * HD_;

  const short* qrow = qb + ((size_t)(b * S_ + q0 + w * 16 + lm)) * H_ + hoff;
  bf16x8 qf0 = *(const bf16x8*)(qrow + lq * 8);
  bf16x8 qf1 = *(const bf16x8*)(qrow + 32 + lq * 8);

  float l_ = 0.f;
  f32x4 o[4];
#pragma unroll
  for (int i = 0; i < 4; ++i) o[i] = (f32x4){0.f, 0.f, 0.f, 0.f};

  int r0 = tid >> 3, c0 = (tid & 7) * 8;
  const short* kg = kb + ((size_t)(b * S_)) * H_ + hoff;
  const short* vg = vtb + ((size_t)(b * H_ + hoff)) * S_;
  const float C1 = 0.1803368802f;  // 0.125 * log2(e)

  bf16x8 kv = *(const bf16x8*)(kg + (size_t)r0 * H_ + c0);
  bf16x8 vv = *(const bf16x8*)(vg + (size_t)r0 * S_ + c0);

  for (int kt = 0; kt < S_; kt += 64) {
    __syncthreads();
    *(bf16x8*)&Ks[r0 * 72 + c0] = kv;
    *(bf16x8*)&Vt[r0 * 72 + c0] = vv;
    __syncthreads();
    if (kt + 64 < S_) {
      kv = *(const bf16x8*)(kg + (size_t)(kt + 64 + r0) * H_ + c0);
      vv = *(const bf16x8*)(vg + (size_t)r0 * S_ + kt + 64 + c0);
    }

    f32x4 st[4];
#pragma unroll
    for (int ni = 0; ni < 4; ++ni) {
      bf16x8 ka0 = *(const bf16x8*)&Ks[(ni * 16 + lm) * 72 + lq * 8];
      bf16x8 ka1 = *(const bf16x8*)&Ks[(ni * 16 + lm) * 72 + 32 + lq * 8];
      f32x4 z = (f32x4){0.f, 0.f, 0.f, 0.f};
      z = __builtin_amdgcn_mfma_f32_16x16x32_bf16(ka0, qf0, z, 0, 0, 0);
      st[ni] = __builtin_amdgcn_mfma_f32_16x16x32_bf16(ka1, qf1, z, 0, 0, 0);
    }

    float rs = 0.f;
#pragma unroll
    for (int ni = 0; ni < 4; ++ni) {
      float p0 = exp2f(st[ni][0] * C1);
      float p1 = exp2f(st[ni][1] * C1);
      float p2 = exp2f(st[ni][2] * C1);
      float p3 = exp2f(st[ni][3] * C1);
      rs += (p0 + p1) + (p2 + p3);
      u32x2 pk = {bfpack(p0, p1), bfpack(p2, p3)};
      *(u32x2*)&Ps[(w * 16 + lm) * 72 + ni * 16 + lq * 4] = pk;
    }
    rs += __shfl_xor(rs, 16);
    rs += __shfl_xor(rs, 32);
    l_ += rs;

    bf16x8 pf0 = *(const bf16x8*)&Ps[(w * 16 + lm) * 72 + lq * 8];
    bf16x8 pf1 = *(const bf16x8*)&Ps[(w * 16 + lm) * 72 + 32 + lq * 8];
#pragma unroll
    for (int nd = 0; nd < 4; ++nd) {
      bf16x8 va0 = *(const bf16x8*)&Vt[(nd * 16 + lm) * 72 + lq * 8];
      bf16x8 va1 = *(const bf16x8*)&Vt[(nd * 16 + lm) * 72 + 32 + lq * 8];
      o[nd] = __builtin_amdgcn_mfma_f32_16x16x32_bf16(va0, pf0, o[nd], 0, 0, 0);
      o[nd] = __builtin_amdgcn_mfma_f32_16x16x32_bf16(va1, pf1, o[nd], 0, 0, 0);
    }
  }

  float inv = 1.0f / l_;
  short* orow = aob + ((size_t)(b * S_ + q0 + w * 16 + lm)) * H_ + hoff;
#pragma unroll
  for (int nd = 0; nd < 4; ++nd) {
    s16x4 pk = {f2bf(o[nd][0] * inv), f2bf(o[nd][1] * inv),
                f2bf(o[nd][2] * inv), f2bf(o[nd][3] * inv)};
    *(s16x4*)(orow + nd * 16 + lq * 4) = pk;
  }
}

// ---------------------------------------------------------------------------
// gate + masked residual + aux partials. 192 thr, x4 vectorized,
// row cached in registers (no second read of x/br/inj).
// ---------------------------------------------------------------------------
__global__ __launch_bounds__(192) void gate_out_k(const float* __restrict__ x,
                                                  const short* __restrict__ br,
                                                  const short* __restrict__ inj,
                                                  const int* __restrict__ mask,
                                                  const float* __restrict__ Wg,
                                                  const float* __restrict__ bg,
                                                  float* __restrict__ out,
                                                  float* __restrict__ paux) {
  int row = blockIdx.x;
  int b = row >> 11;
  size_t base = (size_t)row * H_;
  int h = threadIdx.x * 4;
  float4 xv = *(const float4*)(x + base + h);
  s16x4 brv = *(const s16x4*)(br + base + h);
  s16x4 inv = *(const s16x4*)(inj + base + h);
  float4 wg0 = *(const float4*)(Wg + h);
  float4 wg1 = *(const float4*)(Wg + H_ + h);
  float b0 = bf2f(brv.x), b1 = bf2f(brv.y), b2 = bf2f(brv.z), b3 = bf2f(brv.w);
  float dot = xv.x * wg0.x + xv.y * wg0.y + xv.z * wg0.z + xv.w * wg0.w
            + b0 * wg1.x + b1 * wg1.y + b2 * wg1.z + b3 * wg1.w;
  float d0 = b0 - xv.x, d1 = b1 - xv.y, d2 = b2 - xv.z, d3 = b3 - xv.w;
  float aux = d0 * d0 + d1 * d1 + d2 * d2 + d3 * d3;
  for (int off = 32; off > 0; off >>= 1) {
    dot += __shfl_down(dot, off);
    aux += __shfl_down(aux, off);
  }
  __shared__ float sd[3], sx[3], gsh[2];
  int wid = threadIdx.x >> 6, lane = threadIdx.x & 63;
  if (lane == 0) { sd[wid] = dot; sx[wid] = aux; }
  __syncthreads();
  if (threadIdx.x == 0) {
    float td = sd[0] + sd[1] + sd[2];
    float ta = sx[0] + sx[1] + sx[2];
    gsh[0] = 1.0f / (1.0f + expf(-(td + bg[0])));
    gsh[1] = ta;
  }
  __syncthreads();
  float mf = (mask[b] != 0) ? 1.0f : 0.0f;
  float gm = gsh[0] * mf;
  float v0 = bf2f(inv.x), v1 = bf2f(inv.y), v2 = bf2f(inv.z), v3 = bf2f(inv.w);
  float e0 = __expf(2.f * v0), e1 = __expf(2.f * v1), e2 = __expf(2.f * v2), e3 = __expf(2.f * v3);
  float4 ov;
  ov.x = xv.x + gm * ((e0 - 1.f) / (e0 + 1.f));
  ov.y = xv.y + gm * ((e1 - 1.f) / (e1 + 1.f));
  ov.z = xv.z + gm * ((e2 - 1.f) / (e2 + 1.f));
  ov.w = xv.w + gm * ((e3 - 1.f) / (e3 + 1.f));
  *(float4*)(out + base + h) = ov;
  if (threadIdx.x == 0) paux[row] = mf * gsh[1];
}

__global__ __launch_bounds__(256) void aux_reduce_k(const float* __restrict__ paux,
                                                    const int* __restrict__ mask,
                                                    float* __restrict__ outp) {
  float s = 0.f;
  for (int i = threadIdx.x; i < NROWS; i += 256) s += paux[i];
  for (int off = 32; off > 0; off >>= 1) s += __shfl_down(s, off);
  __shared__ float sw[4];
  int wid = threadIdx.x >> 6, lane = threadIdx.x & 63;
  if (lane == 0) sw[wid] = s;
  __syncthreads();
  if (threadIdx.x == 0) {
    float t = sw[0] + sw[1] + sw[2] + sw[3];
    int nm = (mask[0] != 0) + (mask[1] != 0) + (mask[2] != 0) + (mask[3] != 0);
    if (nm < 1) nm = 1;
    outp[0] = t / ((float)nm * (float)(S_ * H_));
  }
}

// ---------------------------------------------------------------------------
extern "C" void kernel_launch(void* const* d_in, const int* in_sizes, int n_in,
                              void* d_out, int out_size, void* d_ws, size_t ws_size,
                              hipStream_t stream) {
  const float* x     = (const float*)d_in[0];
  const float* prev  = (const float*)d_in[1];
  const int*   mask  = (const int*)d_in[2];
  const float* dw_w  = (const float*)d_in[3];
  const float* dw_b  = (const float*)d_in[4];
  const float* pw_w  = (const float*)d_in[5];
  const float* pw_b  = (const float*)d_in[6];
  const float* cn_g  = (const float*)d_in[7];
  const float* cn_b  = (const float*)d_in[8];
  const float* Wq    = (const float*)d_in[9];
  const float* bq    = (const float*)d_in[10];
  const float* Wk    = (const float*)d_in[11];
  const float* bk    = (const float*)d_in[12];
  const float* Wv    = (const float*)d_in[13];
  const float* bv    = (const float*)d_in[14];
  const float* Wo    = (const float*)d_in[15];
  const float* bo    = (const float*)d_in[16];
  const float* pn_g  = (const float*)d_in[17];
  const float* pn_b  = (const float*)d_in[18];
  const float* Wpost = (const float*)d_in[19];
  const float* bpost = (const float*)d_in[20];
  const float* Wg    = (const float*)d_in[21];
  const float* bg    = (const float*)d_in[22];
  float* out = (float*)d_out;

  short* B0 = (short*)d_ws;     // xb
  short* B1 = B0 + BSH;         // dwo -> qb
  short* B2 = B1 + BSH;         // gelu-out -> aob
  short* B3 = B2 + BSH;         // bridged (until gate)
  short* B4 = B3 + BSH;         // kb -> ao_proj -> pn
  short* B5 = B4 + BSH;         // vtb -> injb
  short* WW = B5 + BSH;         // 6 bf16 weights [pw,q,k,v,o,post]
  float* paux = (float*)(WW + 6 * WSZ);

  dim3 g1(H_ / 128, NROWS / 128, 1);  // (6, 64, 1)
  dim3 g3(H_ / 128, NROWS / 128, 3);  // (6, 64, 3)

  GemmJob jpw   = {B1, WW,           pw_b,  B2, 1, 0};
  GemmJob jq    = {B0, WW + WSZ,     bq,    B1, 0, 0};
  GemmJob jk    = {B3, WW + 2 * WSZ, bk,    B4, 0, 0};
  GemmJob jv    = {B3, WW + 3 * WSZ, bv,    B5, 0, 1};
  GemmJob jo    = {B2, WW + 4 * WSZ, bo,    B4, 0, 0};
  GemmJob jpost = {B4, WW + 5 * WSZ, bpost, B5, 0, 0};

  cvt6_k<<<6 * WSZ / 1024, 256, 0, stream>>>(pw_w, Wq, Wk, Wv, Wo, Wpost, WW);
  cvt_x_k<<<BSH / 1024, 256, 0, stream>>>(x, B0);
  dwconv_k<<<NROWS, 192, 0, stream>>>(prev, dw_w, dw_b, B1);
  gemm_bf2<<<g1, 256, 0, stream>>>(jpw, jpw, jpw);                         // pw + GELU
  ln_bf<<<NROWS, 256, 0, stream>>>(B2, B3, cn_g, cn_b);                    // bridged
  gemm_bf2<<<g3, 256, 0, stream>>>(jq, jk, jv);                            // Q,K,V grouped
  attn3_k<<<dim3(S_ / 128, NH_, B_), 512, 0, stream>>>(B1, B4, B5, B2);    // -> aob
  gemm_bf2<<<g1, 256, 0, stream>>>(jo, jo, jo);                            // o-proj
  ln_bf<<<NROWS, 256, 0, stream>>>(B4, B4, pn_g, pn_b);                    // pn
  gemm_bf2<<<g1, 256, 0, stream>>>(jpost, jpost, jpost);                   // post
  gate_out_k<<<NROWS, 192, 0, stream>>>(x, B3, B5, mask, Wg, bg, out, paux);
  aux_reduce_k<<<1, 256, 0, stream>>>(paux, mask, out + BSH);
}

// Round 6
// 413.526 us; speedup vs baseline: 4.7559x; 1.0138x over previous
//
#include <hip/hip_runtime.h>
#include <math.h>

#define B_ 4
#define S_ 2048
#define H_ 768
#define NH_ 12
#define HD_ 64
#define BSH (B_ * S_ * H_)
#define NROWS (B_ * S_)
#define WSZ (H_ * H_)  // 589824

typedef __attribute__((ext_vector_type(8))) short bf16x8;
typedef __attribute__((ext_vector_type(4))) short s16x4;
typedef __attribute__((ext_vector_type(4))) float f32x4;
typedef __attribute__((ext_vector_type(2))) unsigned u32x2;

__device__ __forceinline__ short f2bf(float f) {
  union { float f; unsigned u; } x; x.f = f;
  unsigned r = x.u + 0x7FFF + ((x.u >> 16) & 1);
  return (short)(r >> 16);
}
__device__ __forceinline__ float bf2f(short s) {
  union { unsigned u; float f; } x;
  x.u = ((unsigned)(unsigned short)s) << 16;
  return x.f;
}
// pack 2 fp32 -> 2 bf16 (truncation) in one v_perm_b32
__device__ __forceinline__ unsigned bfpack(float lo, float hi) {
  union { float f; unsigned u; } a, b; a.f = lo; b.f = hi;
  return __builtin_amdgcn_perm(b.u, a.u, 0x07060302);
}

// async global->LDS, 16B per lane; LDS dst = wave-uniform base + lane*16
typedef __attribute__((address_space(1))) const unsigned int g_u32;
typedef __attribute__((address_space(3))) unsigned int l_u32;
__device__ __forceinline__ void gload16(const void* g, void* l) {
  __builtin_amdgcn_global_load_lds((g_u32*)g, (l_u32*)l, 16, 0, 0);
}

// ---------------------------------------------------------------------------
// fp32 -> bf16 converters
// ---------------------------------------------------------------------------
__global__ __launch_bounds__(256) void cvt_x_k(const float* __restrict__ src,
                                               short* __restrict__ dst) {
  int i = (blockIdx.x * 256 + threadIdx.x) * 4;
  float4 v = *(const float4*)(src + i);
  s16x4 o = {f2bf(v.x), f2bf(v.y), f2bf(v.z), f2bf(v.w)};
  *(s16x4*)(dst + i) = o;
}

__global__ __launch_bounds__(256) void cvt6_k(const float* w0, const float* w1,
                                              const float* w2, const float* w3,
                                              const float* w4, const float* w5,
                                              short* __restrict__ dst) {
  int i = (blockIdx.x * 256 + threadIdx.x) * 4;
  int m = i / WSZ;
  int off = i - m * WSZ;
  const float* s = m == 0 ? w0 : m == 1 ? w1 : m == 2 ? w2 : m == 3 ? w3 : m == 4 ? w4 : w5;
  float4 v = *(const float4*)(s + off);
  s16x4 o = {f2bf(v.x), f2bf(v.y), f2bf(v.z), f2bf(v.w)};
  *(s16x4*)(dst + i) = o;
}

// ---------------------------------------------------------------------------
// depthwise conv1d k=3 pad=1 over seq; vectorized x4, 192 thr (H/4=192)
// ---------------------------------------------------------------------------
__global__ __launch_bounds__(192) void dwconv_k(const float* __restrict__ prev,
                                                const float* __restrict__ w3,
                                                const float* __restrict__ bias,
                                                short* __restrict__ out) {
  int row = blockIdx.x;
  int s = row & (S_ - 1);
  int h = threadIdx.x * 4;
  size_t base = (size_t)row * H_ + h;
  float4 c = *(const float4*)(prev + base);
  float4 wa = *(const float4*)(w3 + h * 3);
  float4 wb = *(const float4*)(w3 + h * 3 + 4);
  float4 wc = *(const float4*)(w3 + h * 3 + 8);
  float4 bi = *(const float4*)(bias + h);
  float4 acc;
  acc.x = bi.x + c.x * wa.y;
  acc.y = bi.y + c.y * wb.x;
  acc.z = bi.z + c.z * wb.w;
  acc.w = bi.w + c.w * wc.z;
  if (s > 0) {
    float4 l = *(const float4*)(prev + base - H_);
    acc.x += l.x * wa.x; acc.y += l.y * wa.w; acc.z += l.z * wb.z; acc.w += l.w * wc.y;
  }
  if (s < S_ - 1) {
    float4 r = *(const float4*)(prev + base + H_);
    acc.x += r.x * wa.z; acc.y += r.y * wb.y; acc.z += r.z * wc.x; acc.w += r.w * wc.w;
  }
  s16x4 o = {f2bf(acc.x), f2bf(acc.y), f2bf(acc.z), f2bf(acc.w)};
  *(s16x4*)(out + base) = o;
}

// ---------------------------------------------------------------------------
// Grouped GEMM (QKV): 128x128 tiles, BK=64, blockIdx.z selects job.
// ---------------------------------------------------------------------------
struct GemmJob {
  const short* A; const short* W; const float* bias; short* C; int act; int tout;
};

__global__ __launch_bounds__(256) void gemm_bf2(GemmJob j0, GemmJob j1, GemmJob j2) {
  GemmJob j = blockIdx.z == 0 ? j0 : (blockIdx.z == 1 ? j1 : j2);
  __shared__ short As[128 * 64];  // 16 KB
  __shared__ short Ws[128 * 64];
  int tid = threadIdx.x, lane = tid & 63, w = tid >> 6;
  int wr = w >> 1, wc = w & 1, lm = lane & 15, lq = lane >> 4;
  int m0 = blockIdx.y * 128, n0 = blockIdx.x * 128;
  int srow = lane >> 3;
  int skc = (lane & 7) * 8;
  const short* gA = j.A + (size_t)(m0 + w * 32 + srow) * H_ + skc;
  const short* gW = j.W + (size_t)(n0 + w * 32 + srow) * H_ + skc;
  short* lA = As + w * 2048;
  short* lW = Ws + w * 2048;

  f32x4 acc[4][4];
#pragma unroll
  for (int i = 0; i < 4; ++i)
#pragma unroll
    for (int jj = 0; jj < 4; ++jj) acc[i][jj] = (f32x4){0.f, 0.f, 0.f, 0.f};

  for (int kt = 0; kt < H_; kt += 64) {
    __syncthreads();
#pragma unroll
    for (int c = 0; c < 4; ++c) {
      gload16(gA + kt + (size_t)(c * 8) * H_, lA + c * 512);
      gload16(gW + kt + (size_t)(c * 8) * H_, lW + c * 512);
    }
    __syncthreads();
#pragma unroll
    for (int kk = 0; kk < 2; ++kk) {
      bf16x8 af[4], wf[4];
#pragma unroll
      for (int i = 0; i < 4; ++i)
        af[i] = *(const bf16x8*)&As[(wr * 64 + i * 16 + lm) * 64 + kk * 32 + lq * 8];
#pragma unroll
      for (int jj = 0; jj < 4; ++jj)
        wf[jj] = *(const bf16x8*)&Ws[(wc * 64 + jj * 16 + lm) * 64 + kk * 32 + lq * 8];
#pragma unroll
      for (int i = 0; i < 4; ++i)
#pragma unroll
        for (int jj = 0; jj < 4; ++jj)
          acc[i][jj] = __builtin_amdgcn_mfma_f32_16x16x32_bf16(af[i], wf[jj], acc[i][jj], 0, 0, 0);
    }
  }

  if (!j.tout) {
#pragma unroll
    for (int jj = 0; jj < 4; ++jj) {
      int col = n0 + wc * 64 + jj * 16 + lm;
      float bn = j.bias[col];
#pragma unroll
      for (int i = 0; i < 4; ++i) {
        int mrow = m0 + wr * 64 + i * 16 + lq * 4;
#pragma unroll
        for (int r = 0; r < 4; ++r) {
          float cv = acc[i][jj][r] + bn;
          if (j.act) cv = 0.5f * cv * (1.0f + erff(cv * 0.70710678118f));
          j.C[(size_t)(mrow + r) * H_ + col] = f2bf(cv);
        }
      }
    }
  } else {
    int b = m0 >> 11;
    int sb = (m0 & (S_ - 1)) + wr * 64;
#pragma unroll
    for (int jj = 0; jj < 4; ++jj) {
      int col = n0 + wc * 64 + jj * 16 + lm;
      float bn = j.bias[col];
      short* cp = j.C + ((size_t)(b * H_ + col)) * S_;
#pragma unroll
      for (int i = 0; i < 4; ++i) {
        int s = sb + i * 16 + lq * 4;
        s16x4 pk = {f2bf(acc[i][jj][0] + bn), f2bf(acc[i][jj][1] + bn),
                    f2bf(acc[i][jj][2] + bn), f2bf(acc[i][jj][3] + bn)};
        *(s16x4*)(cp + s) = pk;
      }
    }
  }
}

// ---------------------------------------------------------------------------
// Single GEMM, 128x64 tile (768 blocks = 3.0/CU): pw/o/post projections.
// 4 waves: 2 m-halves x 2 n-halves; wave = 64m x 32n, acc 4x2.
// ---------------------------------------------------------------------------
__global__ __launch_bounds__(256) void gemm_n64(const short* __restrict__ A,
                                                const short* __restrict__ W,
                                                const float* __restrict__ bias,
                                                short* __restrict__ C, int act) {
  __shared__ short As[128 * 64];  // 16 KB
  __shared__ short Ws[64 * 64];   // 8 KB
  int tid = threadIdx.x, lane = tid & 63, w = tid >> 6;
  int wm = w >> 1, wn = w & 1, lm = lane & 15, lq = lane >> 4;
  int m0 = blockIdx.y * 128, n0 = blockIdx.x * 64;
  const short* gA = A + (size_t)(m0 + w * 32 + (lane >> 3)) * H_ + (lane & 7) * 8;
  const short* gW = W + (size_t)(n0 + w * 16 + (lane >> 3)) * H_ + (lane & 7) * 8;
  short* lA = As + w * 2048;  // 32 rows x 64
  short* lW = Ws + w * 1024;  // 16 rows x 64

  f32x4 acc[4][2];
#pragma unroll
  for (int i = 0; i < 4; ++i)
#pragma unroll
    for (int jj = 0; jj < 2; ++jj) acc[i][jj] = (f32x4){0.f, 0.f, 0.f, 0.f};

  for (int kt = 0; kt < H_; kt += 64) {
    __syncthreads();
#pragma unroll
    for (int c = 0; c < 4; ++c)
      gload16(gA + kt + (size_t)(c * 8) * H_, lA + c * 512);
#pragma unroll
    for (int c = 0; c < 2; ++c)
      gload16(gW + kt + (size_t)(c * 8) * H_, lW + c * 512);
    __syncthreads();
#pragma unroll
    for (int kk = 0; kk < 2; ++kk) {
      bf16x8 af[4], wf[2];
#pragma unroll
      for (int i = 0; i < 4; ++i)
        af[i] = *(const bf16x8*)&As[(wm * 64 + i * 16 + lm) * 64 + kk * 32 + lq * 8];
#pragma unroll
      for (int jj = 0; jj < 2; ++jj)
        wf[jj] = *(const bf16x8*)&Ws[(wn * 32 + jj * 16 + lm) * 64 + kk * 32 + lq * 8];
#pragma unroll
      for (int i = 0; i < 4; ++i)
#pragma unroll
        for (int jj = 0; jj < 2; ++jj)
          acc[i][jj] = __builtin_amdgcn_mfma_f32_16x16x32_bf16(af[i], wf[jj], acc[i][jj], 0, 0, 0);
    }
  }

#pragma unroll
  for (int jj = 0; jj < 2; ++jj) {
    int col = n0 + wn * 32 + jj * 16 + lm;
    float bn = bias[col];
#pragma unroll
    for (int i = 0; i < 4; ++i) {
      int mrow = m0 + wm * 64 + i * 16 + lq * 4;
#pragma unroll
      for (int r = 0; r < 4; ++r) {
        float cv = acc[i][jj][r] + bn;
        if (act) cv = 0.5f * cv * (1.0f + erff(cv * 0.70710678118f));
        C[(size_t)(mrow + r) * H_ + col] = f2bf(cv);
      }
    }
  }
}

// ---------------------------------------------------------------------------
// LayerNorm over last dim (H=768), bf16 in -> bf16 out
// ---------------------------------------------------------------------------
__global__ __launch_bounds__(256) void ln_bf(const short* __restrict__ X,
                                             short* __restrict__ Y,
                                             const float* __restrict__ g,
                                             const float* __restrict__ bb) {
  int row = blockIdx.x;
  size_t base = (size_t)row * H_;
  int h0 = threadIdx.x, h1 = h0 + 256, h2 = h0 + 512;
  float x0 = bf2f(X[base + h0]), x1 = bf2f(X[base + h1]), x2 = bf2f(X[base + h2]);
  float s = x0 + x1 + x2;
  float s2 = x0 * x0 + x1 * x1 + x2 * x2;
  for (int off = 32; off > 0; off >>= 1) {
    s += __shfl_down(s, off);
    s2 += __shfl_down(s2, off);
  }
  __shared__ float sa[4], sq[4], st[2];
  int wid = threadIdx.x >> 6, lane = threadIdx.x & 63;
  if (lane == 0) { sa[wid] = s; sq[wid] = s2; }
  __syncthreads();
  if (threadIdx.x == 0) {
    float ts = sa[0] + sa[1] + sa[2] + sa[3];
    float ts2 = sq[0] + sq[1] + sq[2] + sq[3];
    float mean = ts * (1.0f / H_);
    float var = ts2 * (1.0f / H_) - mean * mean;
    st[0] = mean;
    st[1] = rsqrtf(var + 1e-5f);
  }
  __syncthreads();
  float mean = st[0], rstd = st[1];
  Y[base + h0] = f2bf((x0 - mean) * rstd * g[h0] + bb[h0]);
  Y[base + h1] = f2bf((x1 - mean) * rstd * g[h1] + bb[h1]);
  Y[base + h2] = f2bf((x2 - mean) * rstd * g[h2] + bb[h2]);
}

// ---------------------------------------------------------------------------
// MFMA flash attention v4: 256 thr = 4 waves x 32 q-rows (2 q-groups/wave).
// Q in registers (B operand) -> each Ks/Vt fragment read feeds 2 MFMAs,
// halving shared-tile LDS traffic vs 16q/wave. No online max (bounded scores).
// S^T = K Q^T; O^T = V^T P^T with per-wave Ps[q32][sk64] as PV B-operand.
// ---------------------------------------------------------------------------
__global__ __launch_bounds__(256) void attn4_k(const short* __restrict__ qb,
                                               const short* __restrict__ kb,
                                               const short* __restrict__ vtb,
                                               short* __restrict__ aob) {
  __shared__ short Ks[64 * 72];        // [sk][d]
  __shared__ short Vt[64 * 72];        // [d][sk]
  __shared__ short Ps[128 * 72];       // wave w rows [w*32, +32)
  int tid = threadIdx.x, lane = tid & 63, w = tid >> 6;  // w 0..3
  int lm = lane & 15, lq = lane >> 4;
  int b = blockIdx.z, n = blockIdx.y, q0 = blockIdx.x * 128;
  int hoff = n * HD_;

  bf16x8 qf[2][2];
#pragma unroll
  for (int qg = 0; qg < 2; ++qg) {
    const short* qrow = qb + ((size_t)(b * S_ + q0 + w * 32 + qg * 16 + lm)) * H_ + hoff;
    qf[qg][0] = *(const bf16x8*)(qrow + lq * 8);
    qf[qg][1] = *(const bf16x8*)(qrow + 32 + lq * 8);
  }

  float l_[2] = {0.f, 0.f};
  f32x4 o[4][2];
#pragma unroll
  for (int i = 0; i < 4; ++i)
#pragma unroll
    for (int qg = 0; qg < 2; ++qg) o[i][qg] = (f32x4){0.f, 0.f, 0.f, 0.f};

  // staging: row = tid>>2 (0..63), col = (tid&3)*16 shorts; 2x16B each of K,V
  int r0 = tid >> 2, c0 = (tid & 3) * 16;
  const short* kg = kb + ((size_t)(b * S_)) * H_ + hoff;
  const short* vg = vtb + ((size_t)(b * H_ + hoff)) * S_;
  const float C1 = 0.1803368802f;  // 0.125 * log2(e)

  bf16x8 kv0 = *(const bf16x8*)(kg + (size_t)r0 * H_ + c0);
  bf16x8 kv1 = *(const bf16x8*)(kg + (size_t)r0 * H_ + c0 + 8);
  bf16x8 vv0 = *(const bf16x8*)(vg + (size_t)r0 * S_ + c0);
  bf16x8 vv1 = *(const bf16x8*)(vg + (size_t)r0 * S_ + c0 + 8);

  for (int kt = 0; kt < S_; kt += 64) {
    __syncthreads();
    *(bf16x8*)&Ks[r0 * 72 + c0] = kv0;
    *(bf16x8*)&Ks[r0 * 72 + c0 + 8] = kv1;
    *(bf16x8*)&Vt[r0 * 72 + c0] = vv0;
    *(bf16x8*)&Vt[r0 * 72 + c0 + 8] = vv1;
    __syncthreads();
    if (kt + 64 < S_) {
      kv0 = *(const bf16x8*)(kg + (size_t)(kt + 64 + r0) * H_ + c0);
      kv1 = *(const bf16x8*)(kg + (size_t)(kt + 64 + r0) * H_ + c0 + 8);
      vv0 = *(const bf16x8*)(vg + (size_t)r0 * S_ + kt + 64 + c0);
      vv1 = *(const bf16x8*)(vg + (size_t)r0 * S_ + kt + 64 + c0 + 8);
    }

    // ---- S^T[sk][q]: sk = ni*16 + lq*4 + r, q = lm (per q-group) ----
    f32x4 st[4][2];
#pragma unroll
    for (int ni = 0; ni < 4; ++ni) {
      bf16x8 ka0 = *(const bf16x8*)&Ks[(ni * 16 + lm) * 72 + lq * 8];
      bf16x8 ka1 = *(const bf16x8*)&Ks[(ni * 16 + lm) * 72 + 32 + lq * 8];
#pragma unroll
      for (int qg = 0; qg < 2; ++qg) {
        f32x4 z = (f32x4){0.f, 0.f, 0.f, 0.f};
        z = __builtin_amdgcn_mfma_f32_16x16x32_bf16(ka0, qf[qg][0], z, 0, 0, 0);
        st[ni][qg] = __builtin_amdgcn_mfma_f32_16x16x32_bf16(ka1, qf[qg][1], z, 0, 0, 0);
      }
    }

    // ---- softmax numerator + P pack via v_perm ----
#pragma unroll
    for (int qg = 0; qg < 2; ++qg) {
      float rs = 0.f;
#pragma unroll
      for (int ni = 0; ni < 4; ++ni) {
        float p0 = exp2f(st[ni][qg][0] * C1);
        float p1 = exp2f(st[ni][qg][1] * C1);
        float p2 = exp2f(st[ni][qg][2] * C1);
        float p3 = exp2f(st[ni][qg][3] * C1);
        rs += (p0 + p1) + (p2 + p3);
        u32x2 pk = {bfpack(p0, p1), bfpack(p2, p3)};
        *(u32x2*)&Ps[(w * 32 + qg * 16 + lm) * 72 + ni * 16 + lq * 4] = pk;
      }
      rs += __shfl_xor(rs, 16);
      rs += __shfl_xor(rs, 32);
      l_[qg] += rs;
    }

    // ---- O^T += V^T P^T ----
    bf16x8 pf[2][2];
#pragma unroll
    for (int qg = 0; qg < 2; ++qg) {
      pf[qg][0] = *(const bf16x8*)&Ps[(w * 32 + qg * 16 + lm) * 72 + lq * 8];
      pf[qg][1] = *(const bf16x8*)&Ps[(w * 32 + qg * 16 + lm) * 72 + 32 + lq * 8];
    }
#pragma unroll
    for (int nd = 0; nd < 4; ++nd) {
      bf16x8 va0 = *(const bf16x8*)&Vt[(nd * 16 + lm) * 72 + lq * 8];
      bf16x8 va1 = *(const bf16x8*)&Vt[(nd * 16 + lm) * 72 + 32 + lq * 8];
#pragma unroll
      for (int qg = 0; qg < 2; ++qg) {
        o[nd][qg] = __builtin_amdgcn_mfma_f32_16x16x32_bf16(va0, pf[qg][0], o[nd][qg], 0, 0, 0);
        o[nd][qg] = __builtin_amdgcn_mfma_f32_16x16x32_bf16(va1, pf[qg][1], o[nd][qg], 0, 0, 0);
      }
    }
  }

  // epilogue: q row = q0 + w*32 + qg*16 + lm; d = nd*16 + lq*4 + r
#pragma unroll
  for (int qg = 0; qg < 2; ++qg) {
    float inv = 1.0f / l_[qg];
    short* orow = aob + ((size_t)(b * S_ + q0 + w * 32 + qg * 16 + lm)) * H_ + hoff;
#pragma unroll
    for (int nd = 0; nd < 4; ++nd) {
      s16x4 pk = {f2bf(o[nd][qg][0] * inv), f2bf(o[nd][qg][1] * inv),
                  f2bf(o[nd][qg][2] * inv), f2bf(o[nd][qg][3] * inv)};
      *(s16x4*)(orow + nd * 16 + lq * 4) = pk;
    }
  }
}

// ---------------------------------------------------------------------------
// gate + masked residual + aux partials. 192 thr, x4 vectorized.
// ---------------------------------------------------------------------------
__global__ __launch_bounds__(192) void gate_out_k(const float* __restrict__ x,
                                                  const short* __restrict__ br,
                                                  const short* __restrict__ inj,
                                                  const int* __restrict__ mask,
                                                  const float* __restrict__ Wg,
                                                  const float* __restrict__ bg,
                                                  float* __restrict__ out,
                                                  float* __restrict__ paux) {
  int row = blockIdx.x;
  int b = row >> 11;
  size_t base = (size_t)row * H_;
  int h = threadIdx.x * 4;
  float4 xv = *(const float4*)(x + base + h);
  s16x4 brv = *(const s16x4*)(br + base + h);
  s16x4 inv = *(const s16x4*)(inj + base + h);
  float4 wg0 = *(const float4*)(Wg + h);
  float4 wg1 = *(const float4*)(Wg + H_ + h);
  float b0 = bf2f(brv.x), b1 = bf2f(brv.y), b2 = bf2f(brv.z), b3 = bf2f(brv.w);
  float dot = xv.x * wg0.x + xv.y * wg0.y + xv.z * wg0.z + xv.w * wg0.w
            + b0 * wg1.x + b1 * wg1.y + b2 * wg1.z + b3 * wg1.w;
  float d0 = b0 - xv.x, d1 = b1 - xv.y, d2 = b2 - xv.z, d3 = b3 - xv.w;
  float aux = d0 * d0 + d1 * d1 + d2 * d2 + d3 * d3;
  for (int off = 32; off > 0; off >>= 1) {
    dot += __shfl_down(dot, off);
    aux += __shfl_down(aux, off);
  }
  __shared__ float sd[3], sx[3], gsh[2];
  int wid = threadIdx.x >> 6, lane = threadIdx.x & 63;
  if (lane == 0) { sd[wid] = dot; sx[wid] = aux; }
  __syncthreads();
  if (threadIdx.x == 0) {
    float td = sd[0] + sd[1] + sd[2];
    float ta = sx[0] + sx[1] + sx[2];
    gsh[0] = 1.0f / (1.0f + expf(-(td + bg[0])));
    gsh[1] = ta;
  }
  __syncthreads();
  float mf = (mask[b] != 0) ? 1.0f : 0.0f;
  float gm = gsh[0] * mf;
  float v0 = bf2f(inv.x), v1 = bf2f(inv.y), v2 = bf2f(inv.z), v3 = bf2f(inv.w);
  float e0 = __expf(2.f * v0), e1 = __expf(2.f * v1), e2 = __expf(2.f * v2), e3 = __expf(2.f * v3);
  float4 ov;
  ov.x = xv.x + gm * ((e0 - 1.f) / (e0 + 1.f));
  ov.y = xv.y + gm * ((e1 - 1.f) / (e1 + 1.f));
  ov.z = xv.z + gm * ((e2 - 1.f) / (e2 + 1.f));
  ov.w = xv.w + gm * ((e3 - 1.f) / (e3 + 1.f));
  *(float4*)(out + base + h) = ov;
  if (threadIdx.x == 0) paux[row] = mf * gsh[1];
}

__global__ __launch_bounds__(256) void aux_reduce_k(const float* __restrict__ paux,
                                                    const int* __restrict__ mask,
                                                    float* __restrict__ outp) {
  float s = 0.f;
  for (int i = threadIdx.x; i < NROWS; i += 256) s += paux[i];
  for (int off = 32; off > 0; off >>= 1) s += __shfl_down(s, off);
  __shared__ float sw[4];
  int wid = threadIdx.x >> 6, lane = threadIdx.x & 63;
  if (lane == 0) sw[wid] = s;
  __syncthreads();
  if (threadIdx.x == 0) {
    float t = sw[0] + sw[1] + sw[2] + sw[3];
    int nm = (mask[0] != 0) + (mask[1] != 0) + (mask[2] != 0) + (mask[3] != 0);
    if (nm < 1) nm = 1;
    outp[0] = t / ((float)nm * (float)(S_ * H_));
  }
}

// ---------------------------------------------------------------------------
extern "C" void kernel_launch(void* const* d_in, const int* in_sizes, int n_in,
                              void* d_out, int out_size, void* d_ws, size_t ws_size,
                              hipStream_t stream) {
  const float* x     = (const float*)d_in[0];
  const float* prev  = (const float*)d_in[1];
  const int*   mask  = (const int*)d_in[2];
  const float* dw_w  = (const float*)d_in[3];
  const float* dw_b  = (const float*)d_in[4];
  const float* pw_w  = (const float*)d_in[5];
  const float* pw_b  = (const float*)d_in[6];
  const float* cn_g  = (const float*)d_in[7];
  const float* cn_b  = (const float*)d_in[8];
  const float* Wq    = (const float*)d_in[9];
  const float* bq    = (const float*)d_in[10];
  const float* Wk    = (const float*)d_in[11];
  const float* bk    = (const float*)d_in[12];
  const float* Wv    = (const float*)d_in[13];
  const float* bv    = (const float*)d_in[14];
  const float* Wo    = (const float*)d_in[15];
  const float* bo    = (const float*)d_in[16];
  const float* pn_g  = (const float*)d_in[17];
  const float* pn_b  = (const float*)d_in[18];
  const float* Wpost = (const float*)d_in[19];
  const float* bpost = (const float*)d_in[20];
  const float* Wg    = (const float*)d_in[21];
  const float* bg    = (const float*)d_in[22];
  float* out = (float*)d_out;

  short* B0 = (short*)d_ws;     // xb
  short* B1 = B0 + BSH;         // dwo -> qb
  short* B2 = B1 + BSH;         // gelu-out -> aob
  short* B3 = B2 + BSH;         // bridged (until gate)
  short* B4 = B3 + BSH;         // kb -> ao_proj -> pn
  short* B5 = B4 + BSH;         // vtb -> injb
  short* WW = B5 + BSH;         // 6 bf16 weights [pw,q,k,v,o,post]
  float* paux = (float*)(WW + 6 * WSZ);

  dim3 g3(H_ / 128, NROWS / 128, 3);   // QKV grouped
  dim3 gn(H_ / 64, NROWS / 128, 1);    // (12, 64) single GEMMs

  GemmJob jq = {B0, WW + WSZ,     bq, B1, 0, 0};
  GemmJob jk = {B3, WW + 2 * WSZ, bk, B4, 0, 0};
  GemmJob jv = {B3, WW + 3 * WSZ, bv, B5, 0, 1};

  cvt6_k<<<6 * WSZ / 1024, 256, 0, stream>>>(pw_w, Wq, Wk, Wv, Wo, Wpost, WW);
  cvt_x_k<<<BSH / 1024, 256, 0, stream>>>(x, B0);
  dwconv_k<<<NROWS, 192, 0, stream>>>(prev, dw_w, dw_b, B1);
  gemm_n64<<<gn, 256, 0, stream>>>(B1, WW, pw_b, B2, 1);                   // pw + GELU
  ln_bf<<<NROWS, 256, 0, stream>>>(B2, B3, cn_g, cn_b);                    // bridged
  gemm_bf2<<<g3, 256, 0, stream>>>(jq, jk, jv);                            // Q,K,V grouped
  attn4_k<<<dim3(S_ / 128, NH_, B_), 256, 0, stream>>>(B1, B4, B5, B2);    // -> aob
  gemm_n64<<<gn, 256, 0, stream>>>(B2, WW + 4 * WSZ, bo, B4, 0);           // o-proj
  ln_bf<<<NROWS, 256, 0, stream>>>(B4, B4, pn_g, pn_b);                    // pn
  gemm_n64<<<gn, 256, 0, stream>>>(B4, WW + 5 * WSZ, bpost, B5, 0);        // post
  gate_out_k<<<NROWS, 192, 0, stream>>>(x, B3, B5, mask, Wg, bg, out, paux);
  aux_reduce_k<<<1, 256, 0, stream>>>(paux, mask, out + BSH);
}